// Round 1
// baseline (771.617 us; speedup 1.0000x reference)
//
#include <hip/hip_runtime.h>

// Problem constants
#define BB 2
#define TT 2048
#define CC 768
#define HH 12
#define DD 64
#define NN (BB*TT)            // 4096 rows
#define NQ (BB*HH*TT*DD)      // 3145728 elements per q/k/v tensor
#define CH 32                 // scan chunk (timesteps staged in LDS)

// ---------------------------------------------------------------------------
// Kernel 1: fused q/k/v projection.  Y[n,m] = sum_c X[n,c] * W[m,c]  (x @ W.T)
// Tile 64x64, K-tile 16. LDS stored transposed: Xs[kk][r], Ws[kk][m].
// Output scattered to [B,H,T,D] layout (contiguous per (b,h) chain for scan).
// ---------------------------------------------------------------------------
__global__ __launch_bounds__(256) void proj_qkv_kernel(
    const float* __restrict__ x,
    const float* __restrict__ Wq, const float* __restrict__ Wk,
    const float* __restrict__ Wv,
    float* __restrict__ qo, float* __restrict__ ko, float* __restrict__ vo)
{
    const float* Wsel = (blockIdx.z == 0) ? Wq : ((blockIdx.z == 1) ? Wk : Wv);
    float* osel       = (blockIdx.z == 0) ? qo : ((blockIdx.z == 1) ? ko : vo);

    const int n0 = blockIdx.x * 64;     // row block in [0,4096)
    const int h  = blockIdx.y;          // col block == head (C/64 == H)
    const int tid = threadIdx.x;
    const int tx = tid & 15;            // output col group (4 cols each)
    const int ty = tid >> 4;            // output row group (4 rows each)

    __shared__ float Xs[16][68];        // [kk][row], pad 4 keeps 16B align, spreads banks
    __shared__ float Ws[16][68];        // [kk][col]

    float acc[4][4];
#pragma unroll
    for (int i = 0; i < 4; ++i)
#pragma unroll
        for (int j = 0; j < 4; ++j) acc[i][j] = 0.f;

    const int r   = tid >> 2;           // 0..63 staging row
    const int kk4 = (tid & 3) * 4;      // 0,4,8,12 staging k offset

    for (int k0 = 0; k0 < CC; k0 += 16) {
        float4 xv = *(const float4*)&x[(size_t)(n0 + r) * CC + k0 + kk4];
        float4 wv = *(const float4*)&Wsel[(size_t)(h * 64 + r) * CC + k0 + kk4];
        __syncthreads();                // previous tile fully consumed
        Xs[kk4 + 0][r] = xv.x; Xs[kk4 + 1][r] = xv.y;
        Xs[kk4 + 2][r] = xv.z; Xs[kk4 + 3][r] = xv.w;
        Ws[kk4 + 0][r] = wv.x; Ws[kk4 + 1][r] = wv.y;
        Ws[kk4 + 2][r] = wv.z; Ws[kk4 + 3][r] = wv.w;
        __syncthreads();
#pragma unroll
        for (int kk = 0; kk < 16; ++kk) {
            float4 xr = *(const float4*)&Xs[kk][ty * 4];
            float4 wr = *(const float4*)&Ws[kk][tx * 4];
            float xa[4] = {xr.x, xr.y, xr.z, xr.w};
            float wa[4] = {wr.x, wr.y, wr.z, wr.w};
#pragma unroll
            for (int i = 0; i < 4; ++i)
#pragma unroll
                for (int j = 0; j < 4; ++j) acc[i][j] += xa[i] * wa[j];
        }
    }

    // store: row n -> (b,t); col m = h*64 + d; layout [B,H,T,D]
#pragma unroll
    for (int i = 0; i < 4; ++i) {
        int nn = n0 + ty * 4 + i;
        int b = nn / TT, t = nn % TT;
        float4 o = make_float4(acc[i][0], acc[i][1], acc[i][2], acc[i][3]);
        *(float4*)&osel[(((size_t)b * HH + h) * TT + t) * DD + tx * 4] = o;
    }
}

// ---------------------------------------------------------------------------
// Kernel 2: sequential TTT scan. One block per (b,h) chain. 256 threads:
// thread (i = tid>>2, c = tid&3) owns W[i][c*16 .. c*16+15] in registers.
// Per step: out_i = W_i . q_t ; err_i = W_i . k_t - v_i ; W_i -= lr*err_i*k_t.
// q/k/v staged in double-buffered LDS chunks of CH steps; prefetch loads are
// issued before the compute phase and written to LDS after it (latency hidden).
// Hidden outputs written as [B,T,C] for the final plain GEMM.
// ---------------------------------------------------------------------------
__global__ __launch_bounds__(256) void ttt_scan_kernel(
    const float* __restrict__ qg, const float* __restrict__ kg,
    const float* __restrict__ vg, const float* __restrict__ lr_scale,
    float* __restrict__ hidden)
{
    const int bh = blockIdx.x;
    const int b = bh / HH, h = bh % HH;
    const float eff_lr = 0.01f * lr_scale[h];
    const int tid = threadIdx.x;
    const int i = tid >> 2;             // row 0..63
    const int c = tid & 3;              // col group 0..3

    __shared__ float qs[2][CH * DD];
    __shared__ float ks[2][CH * DD];
    __shared__ float vs[2][CH * DD];
    __shared__ float outs[CH * DD];

    float W[16];
#pragma unroll
    for (int j = 0; j < 16; ++j) W[j] = 0.f;

    const float* qb = qg + (size_t)bh * TT * DD;
    const float* kb = kg + (size_t)bh * TT * DD;
    const float* vb = vg + (size_t)bh * TT * DD;

    // stage chunk 0
    {
        const int p0 = tid * 4, p1 = 1024 + tid * 4;
        *(float4*)&qs[0][p0] = *(const float4*)&qb[p0];
        *(float4*)&qs[0][p1] = *(const float4*)&qb[p1];
        *(float4*)&ks[0][p0] = *(const float4*)&kb[p0];
        *(float4*)&ks[0][p1] = *(const float4*)&kb[p1];
        *(float4*)&vs[0][p0] = *(const float4*)&vb[p0];
        *(float4*)&vs[0][p1] = *(const float4*)&vb[p1];
    }

    int cur = 0;
    const int NCHUNK = TT / CH;         // 64
    for (int ch = 0; ch < NCHUNK; ++ch) {
        __syncthreads();                // staged buf[cur] visible

        // issue prefetch loads for next chunk early (latency hides under compute)
        float4 pq0, pq1, pk0, pk1, pv0, pv1;
        const bool haveNext = (ch + 1 < NCHUNK);
        const int p0 = tid * 4, p1 = 1024 + tid * 4;
        if (haveNext) {
            const float* qn = qb + (size_t)(ch + 1) * (CH * DD);
            const float* kn = kb + (size_t)(ch + 1) * (CH * DD);
            const float* vn = vb + (size_t)(ch + 1) * (CH * DD);
            pq0 = *(const float4*)&qn[p0]; pq1 = *(const float4*)&qn[p1];
            pk0 = *(const float4*)&kn[p0]; pk1 = *(const float4*)&kn[p1];
            pv0 = *(const float4*)&vn[p0]; pv1 = *(const float4*)&vn[p1];
        }

        // ---- compute CH sequential steps from buf[cur] ----
#pragma unroll 4
        for (int tt = 0; tt < CH; ++tt) {
            const int base = tt * DD + c * 16;
            float qv[16], kv[16];
            *(float4*)&qv[0]  = *(const float4*)&qs[cur][base + 0];
            *(float4*)&qv[4]  = *(const float4*)&qs[cur][base + 4];
            *(float4*)&qv[8]  = *(const float4*)&qs[cur][base + 8];
            *(float4*)&qv[12] = *(const float4*)&qs[cur][base + 12];
            *(float4*)&kv[0]  = *(const float4*)&ks[cur][base + 0];
            *(float4*)&kv[4]  = *(const float4*)&ks[cur][base + 4];
            *(float4*)&kv[8]  = *(const float4*)&ks[cur][base + 8];
            *(float4*)&kv[12] = *(const float4*)&ks[cur][base + 12];

            // two partial chains each to shorten FMA dependency chains
            float q0 = 0.f, q1 = 0.f, k0s = 0.f, k1s = 0.f;
#pragma unroll
            for (int j = 0; j < 16; j += 2) {
                q0  += W[j]     * qv[j];
                q1  += W[j + 1] * qv[j + 1];
                k0s += W[j]     * kv[j];
                k1s += W[j + 1] * kv[j + 1];
            }
            float qdot = q0 + q1;
            float kdot = k0s + k1s;
            qdot += __shfl_xor(qdot, 1); qdot += __shfl_xor(qdot, 2);
            kdot += __shfl_xor(kdot, 1); kdot += __shfl_xor(kdot, 2);

            float err = kdot - vs[cur][tt * DD + i];
            float sc = eff_lr * err;
#pragma unroll
            for (int j = 0; j < 16; ++j) W[j] -= sc * kv[j];

            if (c == 0) outs[tt * DD + i] = qdot;
        }

        __syncthreads();                // outs complete; buf[cur] consumed

        // dump outs -> hidden [B,T,C] (col = h*64 + d), coalesced float4
        const int t0 = ch * CH;
        {
            int p = p0;  int ttt = p >> 6, d = p & 63;
            *(float4*)&hidden[((size_t)b * TT + t0 + ttt) * CC + h * DD + d] =
                *(const float4*)&outs[p];
            p = p1; ttt = p >> 6; d = p & 63;
            *(float4*)&hidden[((size_t)b * TT + t0 + ttt) * CC + h * DD + d] =
                *(const float4*)&outs[p];
        }

        // write prefetched regs into the other buffer
        if (haveNext) {
            const int nb = cur ^ 1;
            *(float4*)&qs[nb][p0] = pq0; *(float4*)&qs[nb][p1] = pq1;
            *(float4*)&ks[nb][p0] = pk0; *(float4*)&ks[nb][p1] = pk1;
            *(float4*)&vs[nb][p0] = pv0; *(float4*)&vs[nb][p1] = pv1;
            cur = nb;
        }
    }
}

// ---------------------------------------------------------------------------
// Kernel 3: output projection. out[n,m] = sum_c hidden[n,c] * Wo[m,c]
// Same GEMM structure as kernel 1, plain [N,C] output.
// ---------------------------------------------------------------------------
__global__ __launch_bounds__(256) void out_proj_kernel(
    const float* __restrict__ hidden, const float* __restrict__ Wo,
    float* __restrict__ out)
{
    const int n0 = blockIdx.x * 64;
    const int m0 = blockIdx.y * 64;
    const int tid = threadIdx.x;
    const int tx = tid & 15;
    const int ty = tid >> 4;

    __shared__ float Xs[16][68];
    __shared__ float Ws[16][68];

    float acc[4][4];
#pragma unroll
    for (int i = 0; i < 4; ++i)
#pragma unroll
        for (int j = 0; j < 4; ++j) acc[i][j] = 0.f;

    const int r   = tid >> 2;
    const int kk4 = (tid & 3) * 4;

    for (int k0 = 0; k0 < CC; k0 += 16) {
        float4 xv = *(const float4*)&hidden[(size_t)(n0 + r) * CC + k0 + kk4];
        float4 wv = *(const float4*)&Wo[(size_t)(m0 + r) * CC + k0 + kk4];
        __syncthreads();
        Xs[kk4 + 0][r] = xv.x; Xs[kk4 + 1][r] = xv.y;
        Xs[kk4 + 2][r] = xv.z; Xs[kk4 + 3][r] = xv.w;
        Ws[kk4 + 0][r] = wv.x; Ws[kk4 + 1][r] = wv.y;
        Ws[kk4 + 2][r] = wv.z; Ws[kk4 + 3][r] = wv.w;
        __syncthreads();
#pragma unroll
        for (int kk = 0; kk < 16; ++kk) {
            float4 xr = *(const float4*)&Xs[kk][ty * 4];
            float4 wr = *(const float4*)&Ws[kk][tx * 4];
            float xa[4] = {xr.x, xr.y, xr.z, xr.w};
            float wa[4] = {wr.x, wr.y, wr.z, wr.w};
#pragma unroll
            for (int i = 0; i < 4; ++i)
#pragma unroll
                for (int j = 0; j < 4; ++j) acc[i][j] += xa[i] * wa[j];
        }
    }

#pragma unroll
    for (int i = 0; i < 4; ++i) {
        int nn = n0 + ty * 4 + i;
        float4 o = make_float4(acc[i][0], acc[i][1], acc[i][2], acc[i][3]);
        *(float4*)&out[(size_t)nn * CC + m0 + tx * 4] = o;
    }
}

// ---------------------------------------------------------------------------
extern "C" void kernel_launch(void* const* d_in, const int* in_sizes, int n_in,
                              void* d_out, int out_size, void* d_ws, size_t ws_size,
                              hipStream_t stream) {
    const float* x  = (const float*)d_in[0];
    const float* Wq = (const float*)d_in[1];
    const float* Wk = (const float*)d_in[2];
    const float* Wv = (const float*)d_in[3];
    const float* Wo = (const float*)d_in[4];
    const float* lr = (const float*)d_in[5];

    float* ws = (float*)d_ws;
    float* q      = ws;
    float* k      = ws + (size_t)NQ;
    float* v      = ws + (size_t)2 * NQ;
    float* hidden = ws + (size_t)3 * NQ;   // [B,T,C] fp32

    // 1) q/k/v projections
    proj_qkv_kernel<<<dim3(NN / 64, CC / 64, 3), 256, 0, stream>>>(
        x, Wq, Wk, Wv, q, k, v);

    // 2) sequential scan (24 chains)
    ttt_scan_kernel<<<dim3(BB * HH), 256, 0, stream>>>(q, k, v, lr, hidden);

    // 3) output projection
    out_proj_kernel<<<dim3(NN / 64, CC / 64), 256, 0, stream>>>(
        hidden, Wo, (float*)d_out);
}

// Round 2
// 678.861 us; speedup vs baseline: 1.1366x; 1.1366x over previous
//
#include <hip/hip_runtime.h>

// Problem constants
#define BB 2
#define TT 2048
#define CC 768
#define HH 12
#define DD 64
#define NN (BB*TT)            // 4096 rows
#define NQ (BB*HH*TT*DD)      // 3145728 elements per q/k/v tensor
#define CH 32                 // scan chunk (timesteps staged in LDS)

// async global->LDS: 16B per lane, dest = uniform LDS base + lane*16
#define GLOAD16(g, l)                                                        \
    __builtin_amdgcn_global_load_lds(                                        \
        (const __attribute__((address_space(1))) void*)(g),                  \
        (__attribute__((address_space(3))) void*)(l), 16, 0, 0)

// ---------------------------------------------------------------------------
// Kernel 1: fused q/k/v projection.  Y[n,m] = sum_c X[n,c] * W[m,c]  (x @ W.T)
// Output scattered to [B,H,T,D] layout (contiguous per (b,h) chain for scan).
// ---------------------------------------------------------------------------
__global__ __launch_bounds__(256) void proj_qkv_kernel(
    const float* __restrict__ x,
    const float* __restrict__ Wq, const float* __restrict__ Wk,
    const float* __restrict__ Wv,
    float* __restrict__ qo, float* __restrict__ ko, float* __restrict__ vo)
{
    const float* Wsel = (blockIdx.z == 0) ? Wq : ((blockIdx.z == 1) ? Wk : Wv);
    float* osel       = (blockIdx.z == 0) ? qo : ((blockIdx.z == 1) ? ko : vo);

    const int n0 = blockIdx.x * 64;     // row block in [0,4096)
    const int h  = blockIdx.y;          // col block == head (C/64 == H)
    const int tid = threadIdx.x;
    const int tx = tid & 15;            // output col group (4 cols each)
    const int ty = tid >> 4;            // output row group (4 rows each)

    __shared__ float Xs[16][68];
    __shared__ float Ws[16][68];

    float acc[4][4];
#pragma unroll
    for (int i = 0; i < 4; ++i)
#pragma unroll
        for (int j = 0; j < 4; ++j) acc[i][j] = 0.f;

    const int r   = tid >> 2;           // 0..63 staging row
    const int kk4 = (tid & 3) * 4;      // 0,4,8,12 staging k offset

    for (int k0 = 0; k0 < CC; k0 += 16) {
        float4 xv = *(const float4*)&x[(size_t)(n0 + r) * CC + k0 + kk4];
        float4 wv = *(const float4*)&Wsel[(size_t)(h * 64 + r) * CC + k0 + kk4];
        __syncthreads();
        Xs[kk4 + 0][r] = xv.x; Xs[kk4 + 1][r] = xv.y;
        Xs[kk4 + 2][r] = xv.z; Xs[kk4 + 3][r] = xv.w;
        Ws[kk4 + 0][r] = wv.x; Ws[kk4 + 1][r] = wv.y;
        Ws[kk4 + 2][r] = wv.z; Ws[kk4 + 3][r] = wv.w;
        __syncthreads();
#pragma unroll
        for (int kk = 0; kk < 16; ++kk) {
            float4 xr = *(const float4*)&Xs[kk][ty * 4];
            float4 wr = *(const float4*)&Ws[kk][tx * 4];
            float xa[4] = {xr.x, xr.y, xr.z, xr.w};
            float wa[4] = {wr.x, wr.y, wr.z, wr.w};
#pragma unroll
            for (int i = 0; i < 4; ++i)
#pragma unroll
                for (int j = 0; j < 4; ++j) acc[i][j] += xa[i] * wa[j];
        }
    }

#pragma unroll
    for (int i = 0; i < 4; ++i) {
        int nn = n0 + ty * 4 + i;
        int b = nn / TT, t = nn % TT;
        float4 o = make_float4(acc[i][0], acc[i][1], acc[i][2], acc[i][3]);
        *(float4*)&osel[(((size_t)b * HH + h) * TT + t) * DD + tx * 4] = o;
    }
}

// ---------------------------------------------------------------------------
// Kernel 2: sequential TTT scan, row-sharded.
// Grid: 24 chains x 8 row-groups = 192 blocks, 64 threads (ONE wave).
// Lane l: r = l>>3 (row within group, global W-row = rg*8+r), c = l&7
// (owns cols c*8..c*8+7). Per step: two 8-wide dots + xor{1,2,4} butterfly
// reduce, rank-1 W update. q/k/v double-buffered in LDS via global_load_lds
// issued right after the vmcnt(0) drain (loads fly under 32 steps of compute).
// No __syncthreads needed (single wave). Outputs stored direct to global.
// ---------------------------------------------------------------------------
__global__ __launch_bounds__(64) void ttt_scan8_kernel(
    const float* __restrict__ qg, const float* __restrict__ kg,
    const float* __restrict__ vg, const float* __restrict__ lr_scale,
    float* __restrict__ hidden)
{
    const int bh = blockIdx.x >> 3;        // chain
    const int rg = blockIdx.x & 7;         // row group (8 rows)
    const int b = bh / HH, h = bh % HH;
    const float eff_lr = 0.01f * lr_scale[h];
    const int lane = threadIdx.x;
    const int r = lane >> 3;               // row within group
    const int c = lane & 7;                // col group (8 cols)

    __shared__ float qs[2][CH * DD];       // 8KB each buf
    __shared__ float ks[2][CH * DD];
    __shared__ float vs[2][CH * 8];        // only this block's 8 rows

    const float* qb = qg + (size_t)bh * TT * DD;
    const float* kb = kg + (size_t)bh * TT * DD;
    const float* vb = vg + (size_t)bh * TT * DD;

    float W[8];
#pragma unroll
    for (int j = 0; j < 8; ++j) W[j] = 0.f;

    // ---- staging helper: 17 global_load_lds per chunk ----
    auto issue_stage = [&](int nb, int cn) {
        const float* qsrc = qb + (size_t)cn * (CH * DD);
        const float* ksrc = kb + (size_t)cn * (CH * DD);
#pragma unroll
        for (int m = 0; m < 8; ++m) {
            GLOAD16(qsrc + m * 256 + lane * 4, &qs[nb][m * 256]);
            GLOAD16(ksrc + m * 256 + lane * 4, &ks[nb][m * 256]);
        }
        // v slice: lane l -> vs[nb][l*4..l*4+3] = v[cn*CH + l/2][rg*8 + (l&1)*4 ..]
        const float* vsrc = vb + ((size_t)cn * CH + (lane >> 1)) * DD
                               + rg * 8 + (lane & 1) * 4;
        GLOAD16(vsrc, &vs[nb][0]);
    };

    // hidden base for this block's rows (col = h*64 + rg*8 + r)
    float* hout = hidden + (size_t)b * TT * CC + h * DD + rg * 8 + r;

    issue_stage(0, 0);

    int cur = 0;
    const int NCHUNK = TT / CH;            // 64
    for (int ch = 0; ch < NCHUNK; ++ch) {
        asm volatile("s_waitcnt vmcnt(0)" ::: "memory");   // buf[cur] ready
        if (ch + 1 < NCHUNK) issue_stage(cur ^ 1, ch + 1); // overlap w/ compute

        const float* qq = &qs[cur][0];
        const float* kk = &ks[cur][0];
        const float* vv = &vs[cur][0];
        float* ho = hout + (size_t)(ch * CH) * CC;

        float qA[8], kA[8], qB[8], kB[8];
        // preload step 0
        *(float4*)&qA[0] = *(const float4*)&qq[c * 8];
        *(float4*)&qA[4] = *(const float4*)&qq[c * 8 + 4];
        *(float4*)&kA[0] = *(const float4*)&kk[c * 8];
        *(float4*)&kA[4] = *(const float4*)&kk[c * 8 + 4];

        auto step = [&](int t, const float* qv, const float* kv) {
            float kd0 = 0.f, kd1 = 0.f, qd0 = 0.f, qd1 = 0.f;
#pragma unroll
            for (int j = 0; j < 4; ++j) {
                kd0 += W[j]     * kv[j];
                kd1 += W[j + 4] * kv[j + 4];
                qd0 += W[j]     * qv[j];
                qd1 += W[j + 4] * qv[j + 4];
            }
            float kd = kd0 + kd1, qd = qd0 + qd1;
            kd += __shfl_xor(kd, 1); kd += __shfl_xor(kd, 2); kd += __shfl_xor(kd, 4);
            qd += __shfl_xor(qd, 1); qd += __shfl_xor(qd, 2); qd += __shfl_xor(qd, 4);
            float sc = eff_lr * (kd - vv[t * 8 + r]);
#pragma unroll
            for (int j = 0; j < 8; ++j) W[j] -= sc * kv[j];
            if (c == 0) ho[(size_t)t * CC] = qd;
        };

        // software-pipelined 2-step unroll (named regsets -> all static indices)
#pragma unroll 4
        for (int t = 0; t < CH; t += 2) {
            {   // prefetch t+1 into B
                const int base = (t + 1) * DD + c * 8;
                *(float4*)&qB[0] = *(const float4*)&qq[base];
                *(float4*)&qB[4] = *(const float4*)&qq[base + 4];
                *(float4*)&kB[0] = *(const float4*)&kk[base];
                *(float4*)&kB[4] = *(const float4*)&kk[base + 4];
            }
            step(t, qA, kA);
            if (t + 2 < CH) {   // prefetch t+2 into A
                const int base = (t + 2) * DD + c * 8;
                *(float4*)&qA[0] = *(const float4*)&qq[base];
                *(float4*)&qA[4] = *(const float4*)&qq[base + 4];
                *(float4*)&kA[0] = *(const float4*)&kk[base];
                *(float4*)&kA[4] = *(const float4*)&kk[base + 4];
            }
            step(t + 1, qB, kB);
        }
        cur ^= 1;
    }
}

// ---------------------------------------------------------------------------
// Kernel 3: output projection. out[n,m] = sum_c hidden[n,c] * Wo[m,c]
// ---------------------------------------------------------------------------
__global__ __launch_bounds__(256) void out_proj_kernel(
    const float* __restrict__ hidden, const float* __restrict__ Wo,
    float* __restrict__ out)
{
    const int n0 = blockIdx.x * 64;
    const int m0 = blockIdx.y * 64;
    const int tid = threadIdx.x;
    const int tx = tid & 15;
    const int ty = tid >> 4;

    __shared__ float Xs[16][68];
    __shared__ float Ws[16][68];

    float acc[4][4];
#pragma unroll
    for (int i = 0; i < 4; ++i)
#pragma unroll
        for (int j = 0; j < 4; ++j) acc[i][j] = 0.f;

    const int r   = tid >> 2;
    const int kk4 = (tid & 3) * 4;

    for (int k0 = 0; k0 < CC; k0 += 16) {
        float4 xv = *(const float4*)&hidden[(size_t)(n0 + r) * CC + k0 + kk4];
        float4 wv = *(const float4*)&Wo[(size_t)(m0 + r) * CC + k0 + kk4];
        __syncthreads();
        Xs[kk4 + 0][r] = xv.x; Xs[kk4 + 1][r] = xv.y;
        Xs[kk4 + 2][r] = xv.z; Xs[kk4 + 3][r] = xv.w;
        Ws[kk4 + 0][r] = wv.x; Ws[kk4 + 1][r] = wv.y;
        Ws[kk4 + 2][r] = wv.z; Ws[kk4 + 3][r] = wv.w;
        __syncthreads();
#pragma unroll
        for (int kk = 0; kk < 16; ++kk) {
            float4 xr = *(const float4*)&Xs[kk][ty * 4];
            float4 wr = *(const float4*)&Ws[kk][tx * 4];
            float xa[4] = {xr.x, xr.y, xr.z, xr.w};
            float wa[4] = {wr.x, wr.y, wr.z, wr.w};
#pragma unroll
            for (int i = 0; i < 4; ++i)
#pragma unroll
                for (int j = 0; j < 4; ++j) acc[i][j] += xa[i] * wa[j];
        }
    }

#pragma unroll
    for (int i = 0; i < 4; ++i) {
        int nn = n0 + ty * 4 + i;
        float4 o = make_float4(acc[i][0], acc[i][1], acc[i][2], acc[i][3]);
        *(float4*)&out[(size_t)nn * CC + m0 + tx * 4] = o;
    }
}

// ---------------------------------------------------------------------------
extern "C" void kernel_launch(void* const* d_in, const int* in_sizes, int n_in,
                              void* d_out, int out_size, void* d_ws, size_t ws_size,
                              hipStream_t stream) {
    const float* x  = (const float*)d_in[0];
    const float* Wq = (const float*)d_in[1];
    const float* Wk = (const float*)d_in[2];
    const float* Wv = (const float*)d_in[3];
    const float* Wo = (const float*)d_in[4];
    const float* lr = (const float*)d_in[5];

    float* ws = (float*)d_ws;
    float* q      = ws;
    float* k      = ws + (size_t)NQ;
    float* v      = ws + (size_t)2 * NQ;
    float* hidden = ws + (size_t)3 * NQ;   // [B,T,C] fp32

    // 1) q/k/v projections
    proj_qkv_kernel<<<dim3(NN / 64, CC / 64, 3), 256, 0, stream>>>(
        x, Wq, Wk, Wv, q, k, v);

    // 2) sequential scan, row-sharded: 24 chains x 8 row-groups, 1 wave each
    ttt_scan8_kernel<<<dim3(BB * HH * 8), 64, 0, stream>>>(q, k, v, lr, hidden);

    // 3) output projection
    out_proj_kernel<<<dim3(NN / 64, CC / 64), 256, 0, stream>>>(
        hidden, Wo, (float*)d_out);
}

// Round 3
// 660.283 us; speedup vs baseline: 1.1686x; 1.0281x over previous
//
#include <hip/hip_runtime.h>

// Problem constants
#define BB 2
#define TT 2048
#define CC 768
#define HH 12
#define DD 64
#define NN (BB*TT)            // 4096 rows
#define NQ (BB*HH*TT*DD)      // 3145728 elements per q/k/v tensor
#define CH 32                 // scan chunk (timesteps staged in LDS)

// async global->LDS: 16B per lane, dest = uniform LDS base + lane*16
#define GLOAD16(g, l)                                                        \
    __builtin_amdgcn_global_load_lds(                                        \
        (const __attribute__((address_space(1))) void*)(g),                  \
        (__attribute__((address_space(3))) void*)(l), 16, 0, 0)

// VALU-speed cross-lane add via DPP quad_perm (stays out of the LDS pipe).
// 0xB1 = quad_perm [1,0,3,2] (xor 1); 0x4E = quad_perm [2,3,0,1] (xor 2).
template <int CTRL>
__device__ __forceinline__ float dpp_xadd(float x) {
    int y = __builtin_amdgcn_update_dpp(0, __builtin_bit_cast(int, x),
                                        CTRL, 0xF, 0xF, true);
    return x + __builtin_bit_cast(float, y);
}

// ---------------------------------------------------------------------------
// Kernel 1: fused q/k/v projection.  Y[n,m] = sum_c X[n,c] * W[m,c]  (x @ W.T)
// Output scattered to [B,H,T,D] layout (contiguous per (b,h) chain for scan).
// ---------------------------------------------------------------------------
__global__ __launch_bounds__(256) void proj_qkv_kernel(
    const float* __restrict__ x,
    const float* __restrict__ Wq, const float* __restrict__ Wk,
    const float* __restrict__ Wv,
    float* __restrict__ qo, float* __restrict__ ko, float* __restrict__ vo)
{
    const float* Wsel = (blockIdx.z == 0) ? Wq : ((blockIdx.z == 1) ? Wk : Wv);
    float* osel       = (blockIdx.z == 0) ? qo : ((blockIdx.z == 1) ? ko : vo);

    const int n0 = blockIdx.x * 64;     // row block in [0,4096)
    const int h  = blockIdx.y;          // col block == head (C/64 == H)
    const int tid = threadIdx.x;
    const int tx = tid & 15;            // output col group (4 cols each)
    const int ty = tid >> 4;            // output row group (4 rows each)

    __shared__ float Xs[16][68];
    __shared__ float Ws[16][68];

    float acc[4][4];
#pragma unroll
    for (int i = 0; i < 4; ++i)
#pragma unroll
        for (int j = 0; j < 4; ++j) acc[i][j] = 0.f;

    const int r   = tid >> 2;           // 0..63 staging row
    const int kk4 = (tid & 3) * 4;      // 0,4,8,12 staging k offset

    for (int k0 = 0; k0 < CC; k0 += 16) {
        float4 xv = *(const float4*)&x[(size_t)(n0 + r) * CC + k0 + kk4];
        float4 wv = *(const float4*)&Wsel[(size_t)(h * 64 + r) * CC + k0 + kk4];
        __syncthreads();
        Xs[kk4 + 0][r] = xv.x; Xs[kk4 + 1][r] = xv.y;
        Xs[kk4 + 2][r] = xv.z; Xs[kk4 + 3][r] = xv.w;
        Ws[kk4 + 0][r] = wv.x; Ws[kk4 + 1][r] = wv.y;
        Ws[kk4 + 2][r] = wv.z; Ws[kk4 + 3][r] = wv.w;
        __syncthreads();
#pragma unroll
        for (int kk = 0; kk < 16; ++kk) {
            float4 xr = *(const float4*)&Xs[kk][ty * 4];
            float4 wr = *(const float4*)&Ws[kk][tx * 4];
            float xa[4] = {xr.x, xr.y, xr.z, xr.w};
            float wa[4] = {wr.x, wr.y, wr.z, wr.w};
#pragma unroll
            for (int i = 0; i < 4; ++i)
#pragma unroll
                for (int j = 0; j < 4; ++j) acc[i][j] += xa[i] * wa[j];
        }
    }

#pragma unroll
    for (int i = 0; i < 4; ++i) {
        int nn = n0 + ty * 4 + i;
        int b = nn / TT, t = nn % TT;
        float4 o = make_float4(acc[i][0], acc[i][1], acc[i][2], acc[i][3]);
        *(float4*)&osel[(((size_t)b * HH + h) * TT + t) * DD + tx * 4] = o;
    }
}

// ---------------------------------------------------------------------------
// Kernel 2: sequential TTT scan, row-sharded, DPP reduction.
// Grid: 24 chains x 4 row-groups (16 rows each) = 96 blocks, 64 threads.
// Lane l: r = l>>2 (row within group), c = l&3 (owns cols c*16..c*16+15).
// Per step: 16-wide dots per lane + 2 quad_perm DPP add stages (VALU pipe,
// ~6cy each) replace the 3 dependent ds_swizzle shuffles (~140cy each) that
// dominated round 2's critical path. Rank-1 W update lane-local.
// q/k/v double-buffered in LDS via global_load_lds, issued right after the
// vmcnt(0) drain so the HBM latency hides under 32 steps of compute.
// Single wave -> no __syncthreads. Outputs stored direct to global.
// ---------------------------------------------------------------------------
__global__ __launch_bounds__(64) void ttt_scan16_kernel(
    const float* __restrict__ qg, const float* __restrict__ kg,
    const float* __restrict__ vg, const float* __restrict__ lr_scale,
    float* __restrict__ hidden)
{
    const int bh = blockIdx.x >> 2;        // chain
    const int rg = blockIdx.x & 3;         // row group (16 rows)
    const int b = bh / HH, h = bh % HH;
    const float eff_lr = 0.01f * lr_scale[h];
    const int lane = threadIdx.x;
    const int r = lane >> 2;               // row within group, 0..15
    const int c = lane & 3;                // col quad, 16 cols each

    __shared__ float qs[2][CH * DD];       // 8KB per buf
    __shared__ float ks[2][CH * DD];
    __shared__ float vs[2][CH * 16];       // only this block's 16 rows

    const float* qb = qg + (size_t)bh * TT * DD;
    const float* kb = kg + (size_t)bh * TT * DD;
    const float* vb = vg + (size_t)bh * TT * DD;

    float W[16];
#pragma unroll
    for (int j = 0; j < 16; ++j) W[j] = 0.f;

    // ---- staging: 18 global_load_lds per chunk ----
    auto issue_stage = [&](int nb, int cn) {
        const float* qsrc = qb + (size_t)cn * (CH * DD);
        const float* ksrc = kb + (size_t)cn * (CH * DD);
#pragma unroll
        for (int m = 0; m < 8; ++m) {
            GLOAD16(qsrc + m * 256 + lane * 4, &qs[nb][m * 256]);
            GLOAD16(ksrc + m * 256 + lane * 4, &ks[nb][m * 256]);
        }
        // v rows rg*16..rg*16+15: vs[t*16+j]; lane -> (t=lane>>2, j=(lane&3)*4)
        const float* vsrc0 = vb + ((size_t)cn * CH + (lane >> 2)) * DD
                                + rg * 16 + (lane & 3) * 4;
        GLOAD16(vsrc0, &vs[nb][0]);
        GLOAD16(vsrc0 + (size_t)16 * DD, &vs[nb][256]);
    };

    // hidden base for this block's rows (col = h*64 + rg*16 + r)
    float* hout = hidden + (size_t)b * TT * CC + h * DD + rg * 16 + r;

    issue_stage(0, 0);

    int cur = 0;
    const int NCHUNK = TT / CH;            // 64
    for (int ch = 0; ch < NCHUNK; ++ch) {
        asm volatile("s_waitcnt vmcnt(0)" ::: "memory");   // buf[cur] ready
        if (ch + 1 < NCHUNK) issue_stage(cur ^ 1, ch + 1); // fly under compute

        const float* qq = &qs[cur][0];
        const float* kk = &ks[cur][0];
        const float* vv = &vs[cur][0];
        float* ho = hout + (size_t)(ch * CH) * CC;

        float qA[16], kA[16], qB[16], kB[16];
        // preload step 0
#pragma unroll
        for (int p = 0; p < 4; ++p) {
            *(float4*)&qA[p * 4] = *(const float4*)&qq[c * 16 + p * 4];
            *(float4*)&kA[p * 4] = *(const float4*)&kk[c * 16 + p * 4];
        }

        auto step = [&](int t, const float* qv, const float* kv) {
            float kd0 = 0.f, kd1 = 0.f, qd0 = 0.f, qd1 = 0.f;
#pragma unroll
            for (int j = 0; j < 8; ++j) {
                kd0 += W[j]     * kv[j];
                kd1 += W[j + 8] * kv[j + 8];
                qd0 += W[j]     * qv[j];
                qd1 += W[j + 8] * qv[j + 8];
            }
            float kd = kd0 + kd1, qd = qd0 + qd1;
            kd = dpp_xadd<0xB1>(kd); kd = dpp_xadd<0x4E>(kd);
            qd = dpp_xadd<0xB1>(qd); qd = dpp_xadd<0x4E>(qd);
            float sc = eff_lr * (kd - vv[t * 16 + r]);
#pragma unroll
            for (int j = 0; j < 16; ++j) W[j] -= sc * kv[j];
            if (c == 0) ho[(size_t)t * CC] = qd;
        };

        // software-pipelined 2-step unroll (named regsets -> static indices)
#pragma unroll 4
        for (int t = 0; t < CH; t += 2) {
            {   // prefetch t+1 into B
                const int base = (t + 1) * DD + c * 16;
#pragma unroll
                for (int p = 0; p < 4; ++p) {
                    *(float4*)&qB[p * 4] = *(const float4*)&qq[base + p * 4];
                    *(float4*)&kB[p * 4] = *(const float4*)&kk[base + p * 4];
                }
            }
            step(t, qA, kA);
            if (t + 2 < CH) {   // prefetch t+2 into A
                const int base = (t + 2) * DD + c * 16;
#pragma unroll
                for (int p = 0; p < 4; ++p) {
                    *(float4*)&qA[p * 4] = *(const float4*)&qq[base + p * 4];
                    *(float4*)&kA[p * 4] = *(const float4*)&kk[base + p * 4];
                }
            }
            step(t + 1, qB, kB);
        }
        cur ^= 1;
    }
}

// ---------------------------------------------------------------------------
// Kernel 3: output projection. out[n,m] = sum_c hidden[n,c] * Wo[m,c]
// ---------------------------------------------------------------------------
__global__ __launch_bounds__(256) void out_proj_kernel(
    const float* __restrict__ hidden, const float* __restrict__ Wo,
    float* __restrict__ out)
{
    const int n0 = blockIdx.x * 64;
    const int m0 = blockIdx.y * 64;
    const int tid = threadIdx.x;
    const int tx = tid & 15;
    const int ty = tid >> 4;

    __shared__ float Xs[16][68];
    __shared__ float Ws[16][68];

    float acc[4][4];
#pragma unroll
    for (int i = 0; i < 4; ++i)
#pragma unroll
        for (int j = 0; j < 4; ++j) acc[i][j] = 0.f;

    const int r   = tid >> 2;
    const int kk4 = (tid & 3) * 4;

    for (int k0 = 0; k0 < CC; k0 += 16) {
        float4 xv = *(const float4*)&hidden[(size_t)(n0 + r) * CC + k0 + kk4];
        float4 wv = *(const float4*)&Wo[(size_t)(m0 + r) * CC + k0 + kk4];
        __syncthreads();
        Xs[kk4 + 0][r] = xv.x; Xs[kk4 + 1][r] = xv.y;
        Xs[kk4 + 2][r] = xv.z; Xs[kk4 + 3][r] = xv.w;
        Ws[kk4 + 0][r] = wv.x; Ws[kk4 + 1][r] = wv.y;
        Ws[kk4 + 2][r] = wv.z; Ws[kk4 + 3][r] = wv.w;
        __syncthreads();
#pragma unroll
        for (int kk = 0; kk < 16; ++kk) {
            float4 xr = *(const float4*)&Xs[kk][ty * 4];
            float4 wr = *(const float4*)&Ws[kk][tx * 4];
            float xa[4] = {xr.x, xr.y, xr.z, xr.w};
            float wa[4] = {wr.x, wr.y, wr.z, wr.w};
#pragma unroll
            for (int i = 0; i < 4; ++i)
#pragma unroll
                for (int j = 0; j < 4; ++j) acc[i][j] += xa[i] * wa[j];
        }
    }

#pragma unroll
    for (int i = 0; i < 4; ++i) {
        int nn = n0 + ty * 4 + i;
        float4 o = make_float4(acc[i][0], acc[i][1], acc[i][2], acc[i][3]);
        *(float4*)&out[(size_t)nn * CC + m0 + tx * 4] = o;
    }
}

// ---------------------------------------------------------------------------
extern "C" void kernel_launch(void* const* d_in, const int* in_sizes, int n_in,
                              void* d_out, int out_size, void* d_ws, size_t ws_size,
                              hipStream_t stream) {
    const float* x  = (const float*)d_in[0];
    const float* Wq = (const float*)d_in[1];
    const float* Wk = (const float*)d_in[2];
    const float* Wv = (const float*)d_in[3];
    const float* Wo = (const float*)d_in[4];
    const float* lr = (const float*)d_in[5];

    float* ws = (float*)d_ws;
    float* q      = ws;
    float* k      = ws + (size_t)NQ;
    float* v      = ws + (size_t)2 * NQ;
    float* hidden = ws + (size_t)3 * NQ;   // [B,T,C] fp32

    // 1) q/k/v projections
    proj_qkv_kernel<<<dim3(NN / 64, CC / 64, 3), 256, 0, stream>>>(
        x, Wq, Wk, Wv, q, k, v);

    // 2) sequential scan, row-sharded: 24 chains x 4 row-groups, 1 wave each
    ttt_scan16_kernel<<<dim3(BB * HH * 4), 64, 0, stream>>>(q, k, v, lr, hidden);

    // 3) output projection
    out_proj_kernel<<<dim3(NN / 64, CC / 64), 256, 0, stream>>>(
        hidden, Wo, (float*)d_out);
}

// Round 4
// 462.780 us; speedup vs baseline: 1.6674x; 1.4268x over previous
//
#include <hip/hip_runtime.h>

// Problem constants
#define BB 2
#define TT 2048
#define CC 768
#define HH 12
#define DD 64
#define NN (BB*TT)            // 4096 rows
#define NQ (BB*HH*TT*DD)      // 3145728 elements per q/k/v tensor
#define WSZ (CC*CC)           // 589824 elements per weight
#define CH 32                 // scan chunk (timesteps staged in LDS)

typedef __attribute__((ext_vector_type(8))) short short8;
typedef __attribute__((ext_vector_type(8))) unsigned short ushort8;
typedef __attribute__((ext_vector_type(4))) float f32x4;

// async global->LDS: 16B per lane, dest = uniform wave base + lane*16
#define GLOAD16(g, l)                                                        \
    __builtin_amdgcn_global_load_lds(                                        \
        (const __attribute__((address_space(1))) void*)(g),                  \
        (__attribute__((address_space(3))) void*)(l), 16, 0, 0)

// fp32 -> bf16 RNE
__device__ __forceinline__ unsigned short f2b(float f) {
    unsigned int u = __builtin_bit_cast(unsigned int, f);
    unsigned int r = (u + 0x7FFFu + ((u >> 16) & 1u)) >> 16;
    return (unsigned short)r;
}

// VALU-speed cross-lane add via DPP quad_perm.
// 0xB1 = quad_perm xor1; 0x4E = quad_perm xor2.
template <int CTRL>
__device__ __forceinline__ float dpp_xadd(float x) {
    int y = __builtin_amdgcn_update_dpp(0, __builtin_bit_cast(int, x),
                                        CTRL, 0xF, 0xF, true);
    return x + __builtin_bit_cast(float, y);
}

// ---------------------------------------------------------------------------
// Kernel 0: fp32 -> bf16 conversion, 4 segments (x, Wq, Wk, Wv).
// ---------------------------------------------------------------------------
__global__ __launch_bounds__(256) void cvt4_kernel(
    const float* __restrict__ x,  const float* __restrict__ Wq,
    const float* __restrict__ Wk, const float* __restrict__ Wv,
    unsigned short* __restrict__ xb,  unsigned short* __restrict__ wqb,
    unsigned short* __restrict__ wkb, unsigned short* __restrict__ wvb)
{
    const int seg = blockIdx.y;
    const float* s; unsigned short* d; int n8;
    if      (seg == 0) { s = x;  d = xb;  n8 = NQ  / 8; }
    else if (seg == 1) { s = Wq; d = wqb; n8 = WSZ / 8; }
    else if (seg == 2) { s = Wk; d = wkb; n8 = WSZ / 8; }
    else               { s = Wv; d = wvb; n8 = WSZ / 8; }
    int i = blockIdx.x * 256 + threadIdx.x;
    if (i >= n8) return;
    const float* p = s + (size_t)i * 8;
    ushort8 o;
#pragma unroll
    for (int j = 0; j < 8; ++j) o[j] = f2b(p[j]);
    *(ushort8*)(d + (size_t)i * 8) = o;
}

// single-tensor variant (Wo, converted after proj so its slot can alias Wqb)
__global__ __launch_bounds__(256) void cvt1_kernel(
    const float* __restrict__ s, unsigned short* __restrict__ d, int n8)
{
    int i = blockIdx.x * 256 + threadIdx.x;
    if (i >= n8) return;
    const float* p = s + (size_t)i * 8;
    ushort8 o;
#pragma unroll
    for (int j = 0; j < 8; ++j) o[j] = f2b(p[j]);
    *(ushort8*)(d + (size_t)i * 8) = o;
}

// ---------------------------------------------------------------------------
// bf16 MFMA GEMM:  Y[m,n] = sum_k A[m,k] * B[n,k]   (A @ B^T, both row-major)
// BM=BN=128, BK=64, 256 threads (4 waves, 2x2), wave = 64x64 out = 4x4 frags
// of 16x16, mfma_f32_16x16x32_bf16. LDS [128][64] bf16 per operand with
// chunk-XOR swizzle (c ^= row&7) applied on the *global source* so
// global_load_lds dest stays linear; ds_read_b128 is then ~2-way (free).
// MODE 0: scatter output to q/k/v [B,H,T,D] fp32, select by blockIdx.z.
// MODE 1: row-major fp32 output.
// ---------------------------------------------------------------------------
template <int MODE>
__global__ __launch_bounds__(256) void gemm_bt_kernel(
    const unsigned short* __restrict__ Abf,
    const unsigned short* __restrict__ Bq, const unsigned short* __restrict__ Bk,
    const unsigned short* __restrict__ Bv,
    float* __restrict__ Oq, float* __restrict__ Ok, float* __restrict__ Ov)
{
    const int z = blockIdx.z;
    const unsigned short* Bsel = (z == 0) ? Bq : ((z == 1) ? Bk : Bv);
    float* Osel                = (z == 0) ? Oq : ((z == 1) ? Ok : Ov);

    const int m0 = blockIdx.x * 128;
    const int n0 = blockIdx.y * 128;
    const int tid = threadIdx.x, lane = tid & 63, wid = tid >> 6;
    const int wm = (wid >> 1) * 64, wn = (wid & 1) * 64;

    __shared__ unsigned short As[128 * 64];   // 16 KB
    __shared__ unsigned short Bs[128 * 64];   // 16 KB

    f32x4 acc[4][4];
#pragma unroll
    for (int a = 0; a < 4; ++a)
#pragma unroll
        for (int b = 0; b < 4; ++b) acc[a][b] = (f32x4){0.f, 0.f, 0.f, 0.f};

    for (int kt = 0; kt < CC; kt += 64) {
        // ---- stage A,B tiles (8 x global_load_lds, pre-swizzled source) ----
#pragma unroll
        for (int i = 0; i < 4; ++i) {
            int slot = i * 256 + tid;
            int row = slot >> 3, c = slot & 7;
            int gc = c ^ (row & 7);
            GLOAD16(Abf  + (size_t)(m0 + row) * CC + kt + gc * 8,
                    (char*)As + slot * 16);
            GLOAD16(Bsel + (size_t)(n0 + row) * CC + kt + gc * 8,
                    (char*)Bs + slot * 16);
        }
        asm volatile("s_waitcnt vmcnt(0)" ::: "memory");
        __syncthreads();

        // ---- compute: 2 K-halves x 16 MFMA ----
#pragma unroll
        for (int kh = 0; kh < 2; ++kh) {
            short8 af[4], bf[4];
            const int lc = kh * 4 + (lane >> 4);      // logical 16B chunk
#pragma unroll
            for (int mi = 0; mi < 4; ++mi) {
                int row = wm + mi * 16 + (lane & 15);
                af[mi] = *(const short8*)((const char*)As + row * 128
                                          + ((lc ^ (row & 7)) * 16));
            }
#pragma unroll
            for (int ni = 0; ni < 4; ++ni) {
                int row = wn + ni * 16 + (lane & 15);
                bf[ni] = *(const short8*)((const char*)Bs + row * 128
                                          + ((lc ^ (row & 7)) * 16));
            }
#pragma unroll
            for (int mi = 0; mi < 4; ++mi)
#pragma unroll
                for (int ni = 0; ni < 4; ++ni)
                    acc[mi][ni] = __builtin_amdgcn_mfma_f32_16x16x32_bf16(
                        af[mi], bf[ni], acc[mi][ni], 0, 0, 0);
        }
        __syncthreads();
    }

    // ---- write out. C/D: col = lane&15, row = (lane>>4)*4 + r ----
#pragma unroll
    for (int mi = 0; mi < 4; ++mi) {
#pragma unroll
        for (int ni = 0; ni < 4; ++ni) {
            int n = n0 + wn + ni * 16 + (lane & 15);
            int mbase = m0 + wm + mi * 16 + ((lane >> 4) << 2);
            if (MODE == 0) {
                int h = n >> 6, d = n & 63;
#pragma unroll
                for (int r = 0; r < 4; ++r) {
                    int m = mbase + r;
                    int b = m >> 11, t = m & 2047;
                    Osel[(((size_t)b * HH + h) * TT + t) * DD + d] = acc[mi][ni][r];
                }
            } else {
#pragma unroll
                for (int r = 0; r < 4; ++r)
                    Osel[(size_t)(mbase + r) * CC + n] = acc[mi][ni][r];
            }
        }
    }
}

// ---------------------------------------------------------------------------
// Kernel 2: sequential TTT scan (unchanged structure from round 3; hidden is
// now stored as bf16 to feed the MFMA output projection).
// Grid: 24 chains x 4 row-groups (16 rows) = 96 blocks, 64 threads.
// ---------------------------------------------------------------------------
__global__ __launch_bounds__(64) void ttt_scan16_kernel(
    const float* __restrict__ qg, const float* __restrict__ kg,
    const float* __restrict__ vg, const float* __restrict__ lr_scale,
    unsigned short* __restrict__ hidden)
{
    const int bh = blockIdx.x >> 2;        // chain
    const int rg = blockIdx.x & 3;         // row group (16 rows)
    const int b = bh / HH, h = bh % HH;
    const float eff_lr = 0.01f * lr_scale[h];
    const int lane = threadIdx.x;
    const int r = lane >> 2;               // row within group, 0..15
    const int c = lane & 3;                // col quad, 16 cols each

    __shared__ float qs[2][CH * DD];
    __shared__ float ks[2][CH * DD];
    __shared__ float vs[2][CH * 16];

    const float* qb = qg + (size_t)bh * TT * DD;
    const float* kb = kg + (size_t)bh * TT * DD;
    const float* vb = vg + (size_t)bh * TT * DD;

    float W[16];
#pragma unroll
    for (int j = 0; j < 16; ++j) W[j] = 0.f;

    auto issue_stage = [&](int nb, int cn) {
        const float* qsrc = qb + (size_t)cn * (CH * DD);
        const float* ksrc = kb + (size_t)cn * (CH * DD);
#pragma unroll
        for (int m = 0; m < 8; ++m) {
            GLOAD16(qsrc + m * 256 + lane * 4, &qs[nb][m * 256]);
            GLOAD16(ksrc + m * 256 + lane * 4, &ks[nb][m * 256]);
        }
        const float* vsrc0 = vb + ((size_t)cn * CH + (lane >> 2)) * DD
                                + rg * 16 + (lane & 3) * 4;
        GLOAD16(vsrc0, &vs[nb][0]);
        GLOAD16(vsrc0 + (size_t)16 * DD, &vs[nb][256]);
    };

    unsigned short* hout = hidden + (size_t)b * TT * CC + h * DD + rg * 16 + r;

    issue_stage(0, 0);

    int cur = 0;
    const int NCHUNK = TT / CH;            // 64
    for (int ch = 0; ch < NCHUNK; ++ch) {
        asm volatile("s_waitcnt vmcnt(0)" ::: "memory");
        if (ch + 1 < NCHUNK) issue_stage(cur ^ 1, ch + 1);

        const float* qq = &qs[cur][0];
        const float* kk = &ks[cur][0];
        const float* vv = &vs[cur][0];
        unsigned short* ho = hout + (size_t)(ch * CH) * CC;

        float qA[16], kA[16], qB[16], kB[16];
#pragma unroll
        for (int p = 0; p < 4; ++p) {
            *(float4*)&qA[p * 4] = *(const float4*)&qq[c * 16 + p * 4];
            *(float4*)&kA[p * 4] = *(const float4*)&kk[c * 16 + p * 4];
        }

        auto step = [&](int t, const float* qv, const float* kv) {
            float kd0 = 0.f, kd1 = 0.f, qd0 = 0.f, qd1 = 0.f;
#pragma unroll
            for (int j = 0; j < 8; ++j) {
                kd0 += W[j]     * kv[j];
                kd1 += W[j + 8] * kv[j + 8];
                qd0 += W[j]     * qv[j];
                qd1 += W[j + 8] * qv[j + 8];
            }
            float kd = kd0 + kd1, qd = qd0 + qd1;
            kd = dpp_xadd<0xB1>(kd); kd = dpp_xadd<0x4E>(kd);
            qd = dpp_xadd<0xB1>(qd); qd = dpp_xadd<0x4E>(qd);
            float sc = eff_lr * (kd - vv[t * 16 + r]);
#pragma unroll
            for (int j = 0; j < 16; ++j) W[j] -= sc * kv[j];
            if (c == 0) ho[(size_t)t * CC] = f2b(qd);
        };

#pragma unroll 4
        for (int t = 0; t < CH; t += 2) {
            {   // prefetch t+1 into B
                const int base = (t + 1) * DD + c * 16;
#pragma unroll
                for (int p = 0; p < 4; ++p) {
                    *(float4*)&qB[p * 4] = *(const float4*)&qq[base + p * 4];
                    *(float4*)&kB[p * 4] = *(const float4*)&kk[base + p * 4];
                }
            }
            step(t, qA, kA);
            if (t + 2 < CH) {   // prefetch t+2 into A
                const int base = (t + 2) * DD + c * 16;
#pragma unroll
                for (int p = 0; p < 4; ++p) {
                    *(float4*)&qA[p * 4] = *(const float4*)&qq[base + p * 4];
                    *(float4*)&kA[p * 4] = *(const float4*)&kk[base + p * 4];
                }
            }
            step(t + 1, qB, kB);
        }
        cur ^= 1;
    }
}

// ---------------------------------------------------------------------------
extern "C" void kernel_launch(void* const* d_in, const int* in_sizes, int n_in,
                              void* d_out, int out_size, void* d_ws, size_t ws_size,
                              hipStream_t stream) {
    const float* x  = (const float*)d_in[0];
    const float* Wq = (const float*)d_in[1];
    const float* Wk = (const float*)d_in[2];
    const float* Wv = (const float*)d_in[3];
    const float* Wo = (const float*)d_in[4];
    const float* lr = (const float*)d_in[5];

    float* ws = (float*)d_ws;
    float* q = ws;                          // [B,H,T,D] fp32
    float* k = ws + (size_t)NQ;
    float* v = ws + (size_t)2 * NQ;
    // bf16 region aliased over the 4th NQ-float slab (phased lifetimes):
    //   phase cvt->proj : xb (NQ), wqb/wkb/wvb (3*WSZ) at +NQ
    //   phase scan->out : hidden bf16 (NQ) at +0, wob (WSZ) at +NQ
    unsigned short* rb  = (unsigned short*)(ws + (size_t)3 * NQ);
    unsigned short* xb  = rb;
    unsigned short* wqb = rb + (size_t)NQ;
    unsigned short* wkb = wqb + WSZ;
    unsigned short* wvb = wkb + WSZ;
    unsigned short* hid = rb;               // overlaps xb (dead after proj)
    unsigned short* wob = rb + (size_t)NQ;  // overlaps wqb (dead after proj)

    // 0) fp32 -> bf16 (x, Wq, Wk, Wv)
    cvt4_kernel<<<dim3((NQ / 8 + 255) / 256, 4), 256, 0, stream>>>(
        x, Wq, Wk, Wv, xb, wqb, wkb, wvb);

    // 1) q/k/v projections (bf16 MFMA, fp32 out, scattered to [B,H,T,D])
    gemm_bt_kernel<0><<<dim3(NN / 128, CC / 128, 3), 256, 0, stream>>>(
        xb, wqb, wkb, wvb, q, k, v);

    // 1b) Wo -> bf16 into slot freed by wqb
    cvt1_kernel<<<dim3(WSZ / 8 / 256), 256, 0, stream>>>(Wo, wob, WSZ / 8);

    // 2) sequential scan (hidden written as bf16 [B,T,C])
    ttt_scan16_kernel<<<dim3(BB * HH * 4), 64, 0, stream>>>(q, k, v, lr, hid);

    // 3) output projection (bf16 MFMA, fp32 row-major out)
    gemm_bt_kernel<1><<<dim3(NN / 128, CC / 128, 1), 256, 0, stream>>>(
        hid, wob, wob, wob, (float*)d_out, nullptr, nullptr);
}

// Round 5
// 191.970 us; speedup vs baseline: 4.0195x; 2.4107x over previous
//
#include <hip/hip_runtime.h>

// Problem constants
#define BB 2
#define TT 2048
#define CC 768
#define HH 12
#define DD 64
#define NN (BB*TT)            // 4096 rows
#define NQ (BB*HH*TT*DD)      // 3145728 elements per q/k/v tensor
#define WSZ (CC*CC)           // 589824 per weight
#define NCH 32                // chunks per chain
#define CL 64                 // chunk length (timesteps)

typedef __attribute__((ext_vector_type(8))) short short8;
typedef __attribute__((ext_vector_type(8))) unsigned short ushort8;
typedef __attribute__((ext_vector_type(4))) float f32x4;
typedef unsigned short u16;

// async global->LDS: 16B per lane, dest = uniform wave base + lane*16
#define GLOAD16(g, l)                                                        \
    __builtin_amdgcn_global_load_lds(                                        \
        (const __attribute__((address_space(1))) void*)(g),                  \
        (__attribute__((address_space(3))) void*)(l), 16, 0, 0)

__device__ __forceinline__ u16 f2b(float f) {
    unsigned int u = __builtin_bit_cast(unsigned int, f);
    unsigned int r = (u + 0x7FFFu + ((u >> 16) & 1u)) >> 16;
    return (u16)r;
}
__device__ __forceinline__ float b2f(u16 b) {
    unsigned int u = ((unsigned int)b) << 16;
    return __builtin_bit_cast(float, u);
}
// VALU-speed cross-lane add via DPP quad_perm. 0xB1=xor1, 0x4E=xor2.
template <int CTRL>
__device__ __forceinline__ float dpp_xadd(float x) {
    int y = __builtin_amdgcn_update_dpp(0, __builtin_bit_cast(int, x),
                                        CTRL, 0xF, 0xF, true);
    return x + __builtin_bit_cast(float, y);
}
// Swizzled LDS helpers for [64][64] bf16 row-major tiles (128B rows split in
// 8 x 16B chunks, phys_chunk = chunk ^ (row&7)) -> conflict-free ds_read_b128.
__device__ __forceinline__ void st_sw(u16* buf, int row, int col, u16 v) {
    buf[row * 64 + ((((col >> 3) ^ (row & 7)) << 3) | (col & 7))] = v;
}
__device__ __forceinline__ short8 ld_frag(const u16* buf, int row, int lc) {
    return *(const short8*)&buf[row * 64 + ((lc ^ (row & 7)) << 3)];
}
// plain row-major global fragment (row of 64 bf16, 16B chunk lc)
__device__ __forceinline__ short8 gfrag(const u16* base, int row, int lc) {
    return *(const short8*)&base[row * 64 + lc * 8];
}

// ---------------------------------------------------------------------------
// Kernel 0: fp32 -> bf16 for x, Wq, Wk, Wv, Wo.
// ---------------------------------------------------------------------------
__global__ __launch_bounds__(256) void cvt5_kernel(
    const float* __restrict__ x,  const float* __restrict__ Wq,
    const float* __restrict__ Wk, const float* __restrict__ Wv,
    const float* __restrict__ Wo,
    u16* __restrict__ xb, u16* __restrict__ wqb, u16* __restrict__ wkb,
    u16* __restrict__ wvb, u16* __restrict__ wob)
{
    const int seg = blockIdx.y;
    const float* s; u16* d; int n8;
    if      (seg == 0) { s = x;  d = xb;  n8 = NQ  / 8; }
    else if (seg == 1) { s = Wq; d = wqb; n8 = WSZ / 8; }
    else if (seg == 2) { s = Wk; d = wkb; n8 = WSZ / 8; }
    else if (seg == 3) { s = Wv; d = wvb; n8 = WSZ / 8; }
    else               { s = Wo; d = wob; n8 = WSZ / 8; }
    int i = blockIdx.x * 256 + threadIdx.x;
    if (i >= n8) return;
    const float* p = s + (size_t)i * 8;
    ushort8 o;
#pragma unroll
    for (int j = 0; j < 8; ++j) o[j] = f2b(p[j]);
    *(ushort8*)(d + (size_t)i * 8) = o;
}

// ---------------------------------------------------------------------------
// Kernel 1: q/k/v projection, bf16 MFMA, bf16 output scattered to [B,H,T,D].
// (structure identical to round-4, output dtype changed to bf16)
// ---------------------------------------------------------------------------
__global__ __launch_bounds__(256) void proj_qkv_kernel(
    const u16* __restrict__ xb,
    const u16* __restrict__ wq, const u16* __restrict__ wk,
    const u16* __restrict__ wv,
    u16* __restrict__ qo, u16* __restrict__ ko, u16* __restrict__ vo)
{
    const int z = blockIdx.z;
    const u16* Bsel = (z == 0) ? wq : ((z == 1) ? wk : wv);
    u16* Osel       = (z == 0) ? qo : ((z == 1) ? ko : vo);

    const int m0 = blockIdx.x * 128;
    const int n0 = blockIdx.y * 128;
    const int tid = threadIdx.x, lane = tid & 63, wid = tid >> 6;
    const int wm = (wid >> 1) * 64, wn = (wid & 1) * 64;

    __shared__ u16 As[128 * 64];
    __shared__ u16 Bs[128 * 64];

    f32x4 acc[4][4];
#pragma unroll
    for (int a = 0; a < 4; ++a)
#pragma unroll
        for (int b = 0; b < 4; ++b) acc[a][b] = (f32x4){0.f, 0.f, 0.f, 0.f};

    for (int kt = 0; kt < CC; kt += 64) {
#pragma unroll
        for (int i = 0; i < 4; ++i) {
            int slot = i * 256 + tid;
            int row = slot >> 3, c = slot & 7;
            int gc = c ^ (row & 7);
            GLOAD16(xb   + (size_t)(m0 + row) * CC + kt + gc * 8,
                    (char*)As + slot * 16);
            GLOAD16(Bsel + (size_t)(n0 + row) * CC + kt + gc * 8,
                    (char*)Bs + slot * 16);
        }
        asm volatile("s_waitcnt vmcnt(0)" ::: "memory");
        __syncthreads();

#pragma unroll
        for (int kh = 0; kh < 2; ++kh) {
            short8 af[4], bf[4];
            const int lc = kh * 4 + (lane >> 4);
#pragma unroll
            for (int mi = 0; mi < 4; ++mi) {
                int row = wm + mi * 16 + (lane & 15);
                af[mi] = *(const short8*)((const char*)As + row * 128
                                          + ((lc ^ (row & 7)) * 16));
            }
#pragma unroll
            for (int ni = 0; ni < 4; ++ni) {
                int row = wn + ni * 16 + (lane & 15);
                bf[ni] = *(const short8*)((const char*)Bs + row * 128
                                          + ((lc ^ (row & 7)) * 16));
            }
#pragma unroll
            for (int mi = 0; mi < 4; ++mi)
#pragma unroll
                for (int ni = 0; ni < 4; ++ni)
                    acc[mi][ni] = __builtin_amdgcn_mfma_f32_16x16x32_bf16(
                        af[mi], bf[ni], acc[mi][ni], 0, 0, 0);
        }
        __syncthreads();
    }

#pragma unroll
    for (int mi = 0; mi < 4; ++mi) {
#pragma unroll
        for (int ni = 0; ni < 4; ++ni) {
            int n = n0 + wn + ni * 16 + (lane & 15);
            int mbase = m0 + wm + mi * 16 + ((lane >> 4) << 2);
            int h = n >> 6, d = n & 63;
#pragma unroll
            for (int r = 0; r < 4; ++r) {
                int m = mbase + r;
                int b = m >> 11, t = m & 2047;
                Osel[(((size_t)b * HH + h) * TT + t) * DD + d] =
                    f2b(acc[mi][ni][r]);
            }
        }
    }
}

// ---------------------------------------------------------------------------
// Kernel 2 (phase 1, parallel over 768 chunks): per chunk compute
//   A  = lr * stril(K K^T)          (fp32, LDS, for the solve)
//   S  = stril(Q K^T)               (bf16 -> global)
//   T  = (I + A)^{-1}               (forward substitution; bf16 -> global)
//   Kt = K^T                        (bf16 -> global)
// 4 waves: 2x2 quadrants of the 64x64 gemms; solve: wave w owns cols 16w..,
// 4 lanes per column (g = lane&3 strides s), DPP-quad reduced.
// ---------------------------------------------------------------------------
__global__ __launch_bounds__(256) void ttt_prep_kernel(
    const u16* __restrict__ qb, const u16* __restrict__ kb,
    const float* __restrict__ lr_scale,
    u16* __restrict__ Tg, u16* __restrict__ Sg, u16* __restrict__ Ktg)
{
    const int bx = blockIdx.x;
    const int bh = bx >> 5;               // chain
    const int h = bh % HH;
    const float lr = 0.01f * lr_scale[h];
    const u16* kc = kb + (size_t)bh * TT * DD + (size_t)(bx & 31) * (CL * DD);
    const u16* qc = qb + (size_t)bh * TT * DD + (size_t)(bx & 31) * (CL * DD);
    u16* Tc  = Tg  + (size_t)bx * (CL * CL);
    u16* Sc  = Sg  + (size_t)bx * (CL * CL);
    u16* Ktc = Ktg + (size_t)bx * (CL * CL);

    const int tid = threadIdx.x, lane = tid & 63, wid = tid >> 6;
    const int wm = (wid >> 1) * 32, wn = (wid & 1) * 32;
    const int ar0 = wm + (lane & 15);
    const int br0 = wn + (lane & 15);
    const int lcb = lane >> 4;
    const int or0 = wm + ((lane >> 4) << 2);
    const int oc0 = wn + (lane & 15);

    __shared__ float As[64][68];
    __shared__ float Ts[64][68];

    f32x4 aA[2][2], aS[2][2];
#pragma unroll
    for (int a = 0; a < 2; ++a)
#pragma unroll
        for (int b = 0; b < 2; ++b) {
            aA[a][b] = (f32x4){0.f, 0.f, 0.f, 0.f};
            aS[a][b] = (f32x4){0.f, 0.f, 0.f, 0.f};
        }

    short8 Ka[2][2], Kbf[2][2], Qa[2][2];
#pragma unroll
    for (int i = 0; i < 2; ++i)
#pragma unroll
        for (int kh = 0; kh < 2; ++kh) {
            Ka[i][kh]  = gfrag(kc, ar0 + i * 16, kh * 4 + lcb);
            Kbf[i][kh] = gfrag(kc, br0 + i * 16, kh * 4 + lcb);
            Qa[i][kh]  = gfrag(qc, ar0 + i * 16, kh * 4 + lcb);
        }
#pragma unroll
    for (int kh = 0; kh < 2; ++kh)
#pragma unroll
        for (int mi = 0; mi < 2; ++mi)
#pragma unroll
            for (int ni = 0; ni < 2; ++ni) {
                aA[mi][ni] = __builtin_amdgcn_mfma_f32_16x16x32_bf16(
                    Ka[mi][kh], Kbf[ni][kh], aA[mi][ni], 0, 0, 0);
                aS[mi][ni] = __builtin_amdgcn_mfma_f32_16x16x32_bf16(
                    Qa[mi][kh], Kbf[ni][kh], aS[mi][ni], 0, 0, 0);
            }

#pragma unroll
    for (int mi = 0; mi < 2; ++mi)
#pragma unroll
        for (int ni = 0; ni < 2; ++ni)
#pragma unroll
            for (int r = 0; r < 4; ++r) {
                int t = or0 + mi * 16 + r, s = oc0 + ni * 16;
                As[t][s] = (t > s) ? lr * aA[mi][ni][r] : 0.f;
                Sc[t * 64 + s] = f2b((t > s) ? aS[mi][ni][r] : 0.f);
            }
    // zero T (the solve reads "future" rows multiplied by zero)
    for (int i = tid; i < 64 * 68; i += 256) (&Ts[0][0])[i] = 0.f;
    __syncthreads();

    // forward substitution: T[t][j] = delta(t,j) - sum_{s<t} A[t][s] T[s][j]
    {
        const int j = wid * 16 + (lane >> 2), g = lane & 3;
        for (int t = 0; t < 64; ++t) {
            float sum = 0.f;
            const int mm = (t >> 2) + 1;
            for (int m = 0; m < mm; ++m) {
                const int s = g + 4 * m;
                sum += As[t][s] * Ts[s][j];
            }
            sum = dpp_xadd<0xB1>(sum);
            sum = dpp_xadd<0x4E>(sum);
            if (g == 0) Ts[t][j] = ((t == j) ? 1.f : 0.f) - sum;
        }
    }
    __syncthreads();

    // store T (bf16 row-major [t][s])
    {
        const int t = tid >> 2, s0 = (tid & 3) * 16;
        ushort8 o0, o1;
#pragma unroll
        for (int u = 0; u < 8; ++u) {
            o0[u] = f2b(Ts[t][s0 + u]);
            o1[u] = f2b(Ts[t][s0 + 8 + u]);
        }
        *(ushort8*)&Tc[t * 64 + s0]     = o0;
        *(ushort8*)&Tc[t * 64 + s0 + 8] = o1;
    }
    // store Kt (bf16 [j][t])
    {
        const int j = tid & 63, t0 = (tid >> 6) * 16;
        ushort8 o0, o1;
#pragma unroll
        for (int u = 0; u < 8; ++u) {
            o0[u] = kc[(t0 + u) * 64 + j];
            o1[u] = kc[(t0 + 8 + u) * 64 + j];
        }
        *(ushort8*)&Ktc[j * 64 + t0]     = o0;
        *(ushort8*)&Ktc[j * 64 + t0 + 8] = o1;
    }
}

// ---------------------------------------------------------------------------
// Kernel 3 (phase 2, sequential): one block per chain, W in fp32 accumulator
// registers, 32 chunk iterations of 5 bf16 MFMA gemms:
//   Btn = lr*(V^T - W K^T)   [dim i, time s]   (negated-B)
//   Etn = Btn T^T            [i, t]            (= -E^T)
//   Out = Q W^T + S Etn^T    [t, i] -> hidden bf16
//   W  += Etn Kt^T           (i.e. W -= E^T K)
// Operand tiles T,S,Kt,K,Q,V prefetched from global into register fragments;
// Wb/Btn/Etn relayed through swizzled LDS.
// ---------------------------------------------------------------------------
__global__ __launch_bounds__(256, 1) void ttt_chunk_kernel(
    const u16* __restrict__ qb, const u16* __restrict__ kb,
    const u16* __restrict__ vb,
    const u16* __restrict__ Tg, const u16* __restrict__ Sg,
    const u16* __restrict__ Ktg,
    const float* __restrict__ lr_scale, u16* __restrict__ hid)
{
    const int bh = blockIdx.x;
    const int b = bh / HH, h = bh % HH;
    const float lr = 0.01f * lr_scale[h];
    const int tid = threadIdx.x, lane = tid & 63, wid = tid >> 6;
    const int wm = (wid >> 1) * 32, wn = (wid & 1) * 32;
    const int ar0 = wm + (lane & 15);
    const int br0 = wn + (lane & 15);
    const int lcb = lane >> 4;
    const int or0 = wm + ((lane >> 4) << 2);
    const int oc0 = wn + (lane & 15);

    __shared__ u16 Wb[64 * 64];
    __shared__ u16 Btn[64 * 64];
    __shared__ u16 Etn[64 * 64];

    f32x4 accW[2][2];
#pragma unroll
    for (int a = 0; a < 2; ++a)
#pragma unroll
        for (int c = 0; c < 2; ++c) accW[a][c] = (f32x4){0.f, 0.f, 0.f, 0.f};

    const u16* qch = qb + (size_t)bh * TT * DD;
    const u16* kch = kb + (size_t)bh * TT * DD;
    const u16* vch = vb + (size_t)bh * TT * DD;
    const u16* Tch = Tg + (size_t)bh * NCH * (CL * CL);
    const u16* Sch = Sg + (size_t)bh * NCH * (CL * CL);
    const u16* Kth = Ktg + (size_t)bh * NCH * (CL * CL);
    u16* hch = hid + (size_t)b * TT * CC + h * DD;

#pragma unroll 1
    for (int c = 0; c < NCH; ++c) {
        const u16* kc  = kch + (size_t)c * (CL * DD);
        const u16* qc  = qch + (size_t)c * (CL * DD);
        const u16* vc  = vch + (size_t)c * (CL * DD);
        const u16* Tc  = Tch + (size_t)c * (CL * CL);
        const u16* Sc  = Sch + (size_t)c * (CL * CL);
        const u16* Ktc = Kth + (size_t)c * (CL * CL);

        // ---- prefetch operand fragments (global -> regs) ----
        short8 Kf[2][2], Tf[2][2], Qf[2][2], Sf[2][2], Ktf[2][2];
        uint2 vfr[2][2];
#pragma unroll
        for (int i = 0; i < 2; ++i)
#pragma unroll
            for (int kh = 0; kh < 2; ++kh) {
                Kf[i][kh]  = gfrag(kc,  br0 + i * 16, kh * 4 + lcb);
                Tf[i][kh]  = gfrag(Tc,  br0 + i * 16, kh * 4 + lcb);
                Qf[i][kh]  = gfrag(qc,  ar0 + i * 16, kh * 4 + lcb);
                Sf[i][kh]  = gfrag(Sc,  ar0 + i * 16, kh * 4 + lcb);
                Ktf[i][kh] = gfrag(Ktc, br0 + i * 16, kh * 4 + lcb);
            }
#pragma unroll
        for (int mi = 0; mi < 2; ++mi)
#pragma unroll
            for (int ni = 0; ni < 2; ++ni)
                vfr[mi][ni] = *(const uint2*)&vc[(size_t)(oc0 + ni * 16) * 64
                                                 + or0 + mi * 16];

        // ---- W -> bf16 LDS (swizzled) ----
#pragma unroll
        for (int mi = 0; mi < 2; ++mi)
#pragma unroll
            for (int ni = 0; ni < 2; ++ni)
#pragma unroll
                for (int r = 0; r < 4; ++r)
                    st_sw(Wb, or0 + mi * 16 + r, oc0 + ni * 16,
                          f2b(accW[mi][ni][r]));
        __syncthreads();                                   // b1

        // ---- gemm1: (W K^T)[i,s]; Btn = lr*(V^T - .) ----
        f32x4 a1[2][2];
#pragma unroll
        for (int a = 0; a < 2; ++a)
#pragma unroll
            for (int d = 0; d < 2; ++d) a1[a][d] = (f32x4){0.f, 0.f, 0.f, 0.f};
#pragma unroll
        for (int kh = 0; kh < 2; ++kh) {
            short8 wf[2];
#pragma unroll
            for (int mi = 0; mi < 2; ++mi)
                wf[mi] = ld_frag(Wb, ar0 + mi * 16, kh * 4 + lcb);
#pragma unroll
            for (int mi = 0; mi < 2; ++mi)
#pragma unroll
                for (int ni = 0; ni < 2; ++ni)
                    a1[mi][ni] = __builtin_amdgcn_mfma_f32_16x16x32_bf16(
                        wf[mi], Kf[ni][kh], a1[mi][ni], 0, 0, 0);
        }
#pragma unroll
        for (int mi = 0; mi < 2; ++mi)
#pragma unroll
            for (int ni = 0; ni < 2; ++ni) {
                unsigned int lo = vfr[mi][ni].x, hi = vfr[mi][ni].y;
                u16 ve[4] = {(u16)(lo & 0xFFFF), (u16)(lo >> 16),
                             (u16)(hi & 0xFFFF), (u16)(hi >> 16)};
#pragma unroll
                for (int r = 0; r < 4; ++r) {
                    float val = lr * (b2f(ve[r]) - a1[mi][ni][r]);
                    st_sw(Btn, or0 + mi * 16 + r, oc0 + ni * 16, f2b(val));
                }
            }
        __syncthreads();                                   // b2

        // ---- gemm2: Etn[i,t] = Btn T^T ----
        f32x4 a2[2][2];
#pragma unroll
        for (int a = 0; a < 2; ++a)
#pragma unroll
            for (int d = 0; d < 2; ++d) a2[a][d] = (f32x4){0.f, 0.f, 0.f, 0.f};
#pragma unroll
        for (int kh = 0; kh < 2; ++kh) {
            short8 bt[2];
#pragma unroll
            for (int mi = 0; mi < 2; ++mi)
                bt[mi] = ld_frag(Btn, ar0 + mi * 16, kh * 4 + lcb);
#pragma unroll
            for (int mi = 0; mi < 2; ++mi)
#pragma unroll
                for (int ni = 0; ni < 2; ++ni)
                    a2[mi][ni] = __builtin_amdgcn_mfma_f32_16x16x32_bf16(
                        bt[mi], Tf[ni][kh], a2[mi][ni], 0, 0, 0);
        }
#pragma unroll
        for (int mi = 0; mi < 2; ++mi)
#pragma unroll
            for (int ni = 0; ni < 2; ++ni)
#pragma unroll
                for (int r = 0; r < 4; ++r)
                    st_sw(Etn, or0 + mi * 16 + r, oc0 + ni * 16,
                          f2b(a2[mi][ni][r]));
        __syncthreads();                                   // b4

        // ---- gemm3: Out[t,i] = Q W^T + S Etn^T -> hidden ----
        f32x4 a3[2][2];
#pragma unroll
        for (int a = 0; a < 2; ++a)
#pragma unroll
            for (int d = 0; d < 2; ++d) a3[a][d] = (f32x4){0.f, 0.f, 0.f, 0.f};
#pragma unroll
        for (int kh = 0; kh < 2; ++kh) {
            short8 wbf[2], etb[2];
#pragma unroll
            for (int ni = 0; ni < 2; ++ni) {
                wbf[ni] = ld_frag(Wb,  br0 + ni * 16, kh * 4 + lcb);
                etb[ni] = ld_frag(Etn, br0 + ni * 16, kh * 4 + lcb);
            }
#pragma unroll
            for (int mi = 0; mi < 2; ++mi)
#pragma unroll
                for (int ni = 0; ni < 2; ++ni) {
                    a3[mi][ni] = __builtin_amdgcn_mfma_f32_16x16x32_bf16(
                        Qf[mi][kh], wbf[ni], a3[mi][ni], 0, 0, 0);
                    a3[mi][ni] = __builtin_amdgcn_mfma_f32_16x16x32_bf16(
                        Sf[mi][kh], etb[ni], a3[mi][ni], 0, 0, 0);
                }
        }
#pragma unroll
        for (int mi = 0; mi < 2; ++mi)
#pragma unroll
            for (int ni = 0; ni < 2; ++ni)
#pragma unroll
                for (int r = 0; r < 4; ++r)
                    hch[(size_t)(c * CL + or0 + mi * 16 + r) * CC
                        + oc0 + ni * 16] = f2b(a3[mi][ni][r]);

        // ---- gemm5: W += Etn Kt^T ----
#pragma unroll
        for (int kh = 0; kh < 2; ++kh) {
            short8 eta[2];
#pragma unroll
            for (int mi = 0; mi < 2; ++mi)
                eta[mi] = ld_frag(Etn, ar0 + mi * 16, kh * 4 + lcb);
#pragma unroll
            for (int mi = 0; mi < 2; ++mi)
#pragma unroll
                for (int ni = 0; ni < 2; ++ni)
                    accW[mi][ni] = __builtin_amdgcn_mfma_f32_16x16x32_bf16(
                        eta[mi], Ktf[ni][kh], accW[mi][ni], 0, 0, 0);
        }
        __syncthreads();                                   // b5
    }
}

// ---------------------------------------------------------------------------
// Kernel 4: output projection (bf16 MFMA, fp32 row-major out).
// ---------------------------------------------------------------------------
__global__ __launch_bounds__(256) void out_proj_kernel(
    const u16* __restrict__ hid, const u16* __restrict__ wo,
    float* __restrict__ out)
{
    const int m0 = blockIdx.x * 128;
    const int n0 = blockIdx.y * 128;
    const int tid = threadIdx.x, lane = tid & 63, wid = tid >> 6;
    const int wm = (wid >> 1) * 64, wn = (wid & 1) * 64;

    __shared__ u16 As[128 * 64];
    __shared__ u16 Bs[128 * 64];

    f32x4 acc[4][4];
#pragma unroll
    for (int a = 0; a < 4; ++a)
#pragma unroll
        for (int b = 0; b < 4; ++b) acc[a][b] = (f32x4){0.f, 0.f, 0.f, 0.f};

    for (int kt = 0; kt < CC; kt += 64) {
#pragma unroll
        for (int i = 0; i < 4; ++i) {
            int slot = i * 256 + tid;
            int row = slot >> 3, c = slot & 7;
            int gc = c ^ (row & 7);
            GLOAD16(hid + (size_t)(m0 + row) * CC + kt + gc * 8,
                    (char*)As + slot * 16);
            GLOAD16(wo  + (size_t)(n0 + row) * CC + kt + gc * 8,
                    (char*)Bs + slot * 16);
        }
        asm volatile("s_waitcnt vmcnt(0)" ::: "memory");
        __syncthreads();

#pragma unroll
        for (int kh = 0; kh < 2; ++kh) {
            short8 af[4], bf[4];
            const int lc = kh * 4 + (lane >> 4);
#pragma unroll
            for (int mi = 0; mi < 4; ++mi) {
                int row = wm + mi * 16 + (lane & 15);
                af[mi] = *(const short8*)((const char*)As + row * 128
                                          + ((lc ^ (row & 7)) * 16));
            }
#pragma unroll
            for (int ni = 0; ni < 4; ++ni) {
                int row = wn + ni * 16 + (lane & 15);
                bf[ni] = *(const short8*)((const char*)Bs + row * 128
                                          + ((lc ^ (row & 7)) * 16));
            }
#pragma unroll
            for (int mi = 0; mi < 4; ++mi)
#pragma unroll
                for (int ni = 0; ni < 4; ++ni)
                    acc[mi][ni] = __builtin_amdgcn_mfma_f32_16x16x32_bf16(
                        af[mi], bf[ni], acc[mi][ni], 0, 0, 0);
        }
        __syncthreads();
    }

#pragma unroll
    for (int mi = 0; mi < 4; ++mi) {
#pragma unroll
        for (int ni = 0; ni < 4; ++ni) {
            int n = n0 + wn + ni * 16 + (lane & 15);
            int mbase = m0 + wm + mi * 16 + ((lane >> 4) << 2);
#pragma unroll
            for (int r = 0; r < 4; ++r)
                out[(size_t)(mbase + r) * CC + n] = acc[mi][ni][r];
        }
    }
}

// ---------------------------------------------------------------------------
extern "C" void kernel_launch(void* const* d_in, const int* in_sizes, int n_in,
                              void* d_out, int out_size, void* d_ws, size_t ws_size,
                              hipStream_t stream) {
    const float* x  = (const float*)d_in[0];
    const float* Wq = (const float*)d_in[1];
    const float* Wk = (const float*)d_in[2];
    const float* Wv = (const float*)d_in[3];
    const float* Wo = (const float*)d_in[4];
    const float* lr = (const float*)d_in[5];

    // workspace layout (all bf16): 7*NQ + 4*WSZ ushorts = 48.8 MB
    u16* us  = (u16*)d_ws;
    u16* qb  = us;
    u16* kbw = us + (size_t)NQ;
    u16* vbw = us + (size_t)2 * NQ;
    u16* xb  = us + (size_t)3 * NQ;   // reused as hidden after proj
    u16* Tg  = us + (size_t)4 * NQ;
    u16* Sg  = us + (size_t)5 * NQ;
    u16* Ktg = us + (size_t)6 * NQ;
    u16* wqb = us + (size_t)7 * NQ;
    u16* wkb = wqb + WSZ;
    u16* wvb = wkb + WSZ;
    u16* wob = wvb + WSZ;
    u16* hid = xb;

    // 0) fp32 -> bf16
    cvt5_kernel<<<dim3((NQ / 8 + 255) / 256, 5), 256, 0, stream>>>(
        x, Wq, Wk, Wv, Wo, xb, wqb, wkb, wvb, wob);

    // 1) q/k/v projections (bf16 out, [B,H,T,D])
    proj_qkv_kernel<<<dim3(NN / 128, CC / 128, 3), 256, 0, stream>>>(
        xb, wqb, wkb, wvb, qb, kbw, vbw);

    // 2) phase 1: per-chunk T, S, Kt (768 parallel blocks)
    ttt_prep_kernel<<<dim3(BB * HH * NCH), 256, 0, stream>>>(
        qb, kbw, lr, Tg, Sg, Ktg);

    // 3) phase 2: sequential chunk scan, 24 blocks
    ttt_chunk_kernel<<<dim3(BB * HH), 256, 0, stream>>>(
        qb, kbw, vbw, Tg, Sg, Ktg, lr, hid);

    // 4) output projection
    out_proj_kernel<<<dim3(NN / 128, CC / 128), 256, 0, stream>>>(
        hid, wob, (float*)d_out);
}

// Round 6
// 160.839 us; speedup vs baseline: 4.7974x; 1.1936x over previous
//
#include <hip/hip_runtime.h>

// Problem constants
#define BB 2
#define TT 2048
#define CC 768
#define HH 12
#define DD 64
#define NN (BB*TT)            // 4096 rows
#define NQ (BB*HH*TT*DD)      // 3145728 elements per q/k/v tensor
#define WSZ (CC*CC)           // 589824 per weight
#define NCH 32                // chunks per chain
#define CL 64                 // chunk length (timesteps)

typedef __attribute__((ext_vector_type(8))) short short8;
typedef __attribute__((ext_vector_type(8))) unsigned short ushort8;
typedef __attribute__((ext_vector_type(4))) float f32x4;
typedef unsigned short u16;

// async global->LDS: 16B per lane, dest = uniform wave base + lane*16
#define GLOAD16(g, l)                                                        \
    __builtin_amdgcn_global_load_lds(                                        \
        (const __attribute__((address_space(1))) void*)(g),                  \
        (__attribute__((address_space(3))) void*)(l), 16, 0, 0)

__device__ __forceinline__ u16 f2b(float f) {
    unsigned int u = __builtin_bit_cast(unsigned int, f);
    unsigned int r = (u + 0x7FFFu + ((u >> 16) & 1u)) >> 16;
    return (u16)r;
}
__device__ __forceinline__ float b2f(u16 b) {
    unsigned int u = ((unsigned int)b) << 16;
    return __builtin_bit_cast(float, u);
}
// VALU-speed cross-lane add via DPP quad_perm. 0xB1=xor1, 0x4E=xor2.
template <int CTRL>
__device__ __forceinline__ float dpp_xadd(float x) {
    int y = __builtin_amdgcn_update_dpp(0, __builtin_bit_cast(int, x),
                                        CTRL, 0xF, 0xF, true);
    return x + __builtin_bit_cast(float, y);
}
// Swizzled LDS helpers for [64][64] bf16 row-major tiles (128B rows split in
// 8 x 16B chunks, phys_chunk = chunk ^ (row&7)) -> conflict-free ds_read_b128.
__device__ __forceinline__ void st_sw(u16* buf, int row, int col, u16 v) {
    buf[row * 64 + ((((col >> 3) ^ (row & 7)) << 3) | (col & 7))] = v;
}
__device__ __forceinline__ short8 ld_frag(const u16* buf, int row, int lc) {
    return *(const short8*)&buf[row * 64 + ((lc ^ (row & 7)) << 3)];
}
// swizzled 8B read (4 bf16) at (row, col), col%8 in {0,4}
__device__ __forceinline__ uint2 ld_v8(const u16* buf, int row, int col) {
    return *(const uint2*)&buf[row * 64
                               + ((((col >> 3) ^ (row & 7)) << 3) | (col & 7))];
}
// plain row-major global fragment (row of 64 bf16, 16B chunk lc)
__device__ __forceinline__ short8 gfrag(const u16* base, int row, int lc) {
    return *(const short8*)&base[row * 64 + lc * 8];
}

// ---------------------------------------------------------------------------
// Kernel 0: fp32 -> bf16 for x, Wq, Wk, Wv, Wo.
// ---------------------------------------------------------------------------
__global__ __launch_bounds__(256) void cvt5_kernel(
    const float* __restrict__ x,  const float* __restrict__ Wq,
    const float* __restrict__ Wk, const float* __restrict__ Wv,
    const float* __restrict__ Wo,
    u16* __restrict__ xb, u16* __restrict__ wqb, u16* __restrict__ wkb,
    u16* __restrict__ wvb, u16* __restrict__ wob)
{
    const int seg = blockIdx.y;
    const float* s; u16* d; int n8;
    if      (seg == 0) { s = x;  d = xb;  n8 = NQ  / 8; }
    else if (seg == 1) { s = Wq; d = wqb; n8 = WSZ / 8; }
    else if (seg == 2) { s = Wk; d = wkb; n8 = WSZ / 8; }
    else if (seg == 3) { s = Wv; d = wvb; n8 = WSZ / 8; }
    else               { s = Wo; d = wob; n8 = WSZ / 8; }
    int i = blockIdx.x * 256 + threadIdx.x;
    if (i >= n8) return;
    const float* p = s + (size_t)i * 8;
    ushort8 o;
#pragma unroll
    for (int j = 0; j < 8; ++j) o[j] = f2b(p[j]);
    *(ushort8*)(d + (size_t)i * 8) = o;
}

// ---------------------------------------------------------------------------
// Kernel 1: q/k/v projection, bf16 MFMA, bf16 output scattered to [B,H,T,D].
// ---------------------------------------------------------------------------
__global__ __launch_bounds__(256) void proj_qkv_kernel(
    const u16* __restrict__ xb,
    const u16* __restrict__ wq, const u16* __restrict__ wk,
    const u16* __restrict__ wv,
    u16* __restrict__ qo, u16* __restrict__ ko, u16* __restrict__ vo)
{
    const int z = blockIdx.z;
    const u16* Bsel = (z == 0) ? wq : ((z == 1) ? wk : wv);
    u16* Osel       = (z == 0) ? qo : ((z == 1) ? ko : vo);

    const int m0 = blockIdx.x * 128;
    const int n0 = blockIdx.y * 128;
    const int tid = threadIdx.x, lane = tid & 63, wid = tid >> 6;
    const int wm = (wid >> 1) * 64, wn = (wid & 1) * 64;

    __shared__ u16 As[128 * 64];
    __shared__ u16 Bs[128 * 64];

    f32x4 acc[4][4];
#pragma unroll
    for (int a = 0; a < 4; ++a)
#pragma unroll
        for (int b = 0; b < 4; ++b) acc[a][b] = (f32x4){0.f, 0.f, 0.f, 0.f};

    for (int kt = 0; kt < CC; kt += 64) {
#pragma unroll
        for (int i = 0; i < 4; ++i) {
            int slot = i * 256 + tid;
            int row = slot >> 3, c = slot & 7;
            int gc = c ^ (row & 7);
            GLOAD16(xb   + (size_t)(m0 + row) * CC + kt + gc * 8,
                    (char*)As + slot * 16);
            GLOAD16(Bsel + (size_t)(n0 + row) * CC + kt + gc * 8,
                    (char*)Bs + slot * 16);
        }
        asm volatile("s_waitcnt vmcnt(0)" ::: "memory");
        __syncthreads();

#pragma unroll
        for (int kh = 0; kh < 2; ++kh) {
            short8 af[4], bf[4];
            const int lc = kh * 4 + (lane >> 4);
#pragma unroll
            for (int mi = 0; mi < 4; ++mi) {
                int row = wm + mi * 16 + (lane & 15);
                af[mi] = *(const short8*)((const char*)As + row * 128
                                          + ((lc ^ (row & 7)) * 16));
            }
#pragma unroll
            for (int ni = 0; ni < 4; ++ni) {
                int row = wn + ni * 16 + (lane & 15);
                bf[ni] = *(const short8*)((const char*)Bs + row * 128
                                          + ((lc ^ (row & 7)) * 16));
            }
#pragma unroll
            for (int mi = 0; mi < 4; ++mi)
#pragma unroll
                for (int ni = 0; ni < 4; ++ni)
                    acc[mi][ni] = __builtin_amdgcn_mfma_f32_16x16x32_bf16(
                        af[mi], bf[ni], acc[mi][ni], 0, 0, 0);
        }
        __syncthreads();
    }

#pragma unroll
    for (int mi = 0; mi < 4; ++mi) {
#pragma unroll
        for (int ni = 0; ni < 4; ++ni) {
            int n = n0 + wn + ni * 16 + (lane & 15);
            int mbase = m0 + wm + mi * 16 + ((lane >> 4) << 2);
            int h = n >> 6, d = n & 63;
#pragma unroll
            for (int r = 0; r < 4; ++r) {
                int m = mbase + r;
                int b = m >> 11, t = m & 2047;
                Osel[(((size_t)b * HH + h) * TT + t) * DD + d] =
                    f2b(acc[mi][ni][r]);
            }
        }
    }
}

// ---------------------------------------------------------------------------
// Kernel 2 (phase 1, parallel over 768 chunks): per chunk compute
//   A  = lr * stril(K K^T), S = stril(Q K^T), T = (I+A)^{-1}, Kt = K^T.
// ---------------------------------------------------------------------------
__global__ __launch_bounds__(256) void ttt_prep_kernel(
    const u16* __restrict__ qb, const u16* __restrict__ kb,
    const float* __restrict__ lr_scale,
    u16* __restrict__ Tg, u16* __restrict__ Sg, u16* __restrict__ Ktg)
{
    const int bx = blockIdx.x;
    const int bh = bx >> 5;               // chain
    const int h = bh % HH;
    const float lr = 0.01f * lr_scale[h];
    const u16* kc = kb + (size_t)bh * TT * DD + (size_t)(bx & 31) * (CL * DD);
    const u16* qc = qb + (size_t)bh * TT * DD + (size_t)(bx & 31) * (CL * DD);
    u16* Tc  = Tg  + (size_t)bx * (CL * CL);
    u16* Sc  = Sg  + (size_t)bx * (CL * CL);
    u16* Ktc = Ktg + (size_t)bx * (CL * CL);

    const int tid = threadIdx.x, lane = tid & 63, wid = tid >> 6;
    const int wm = (wid >> 1) * 32, wn = (wid & 1) * 32;
    const int ar0 = wm + (lane & 15);
    const int br0 = wn + (lane & 15);
    const int lcb = lane >> 4;
    const int or0 = wm + ((lane >> 4) << 2);
    const int oc0 = wn + (lane & 15);

    __shared__ float As[64][68];
    __shared__ float Ts[64][68];

    f32x4 aA[2][2], aS[2][2];
#pragma unroll
    for (int a = 0; a < 2; ++a)
#pragma unroll
        for (int b = 0; b < 2; ++b) {
            aA[a][b] = (f32x4){0.f, 0.f, 0.f, 0.f};
            aS[a][b] = (f32x4){0.f, 0.f, 0.f, 0.f};
        }

    short8 Ka[2][2], Kbf[2][2], Qa[2][2];
#pragma unroll
    for (int i = 0; i < 2; ++i)
#pragma unroll
        for (int kh = 0; kh < 2; ++kh) {
            Ka[i][kh]  = gfrag(kc, ar0 + i * 16, kh * 4 + lcb);
            Kbf[i][kh] = gfrag(kc, br0 + i * 16, kh * 4 + lcb);
            Qa[i][kh]  = gfrag(qc, ar0 + i * 16, kh * 4 + lcb);
        }
#pragma unroll
    for (int kh = 0; kh < 2; ++kh)
#pragma unroll
        for (int mi = 0; mi < 2; ++mi)
#pragma unroll
            for (int ni = 0; ni < 2; ++ni) {
                aA[mi][ni] = __builtin_amdgcn_mfma_f32_16x16x32_bf16(
                    Ka[mi][kh], Kbf[ni][kh], aA[mi][ni], 0, 0, 0);
                aS[mi][ni] = __builtin_amdgcn_mfma_f32_16x16x32_bf16(
                    Qa[mi][kh], Kbf[ni][kh], aS[mi][ni], 0, 0, 0);
            }

#pragma unroll
    for (int mi = 0; mi < 2; ++mi)
#pragma unroll
        for (int ni = 0; ni < 2; ++ni)
#pragma unroll
            for (int r = 0; r < 4; ++r) {
                int t = or0 + mi * 16 + r, s = oc0 + ni * 16;
                As[t][s] = (t > s) ? lr * aA[mi][ni][r] : 0.f;
                Sc[t * 64 + s] = f2b((t > s) ? aS[mi][ni][r] : 0.f);
            }
    // zero T (the solve reads "future" rows multiplied by zero)
    for (int i = tid; i < 64 * 68; i += 256) (&Ts[0][0])[i] = 0.f;
    __syncthreads();

    // forward substitution: T[t][j] = delta(t,j) - sum_{s<t} A[t][s] T[s][j]
    {
        const int j = wid * 16 + (lane >> 2), g = lane & 3;
        for (int t = 0; t < 64; ++t) {
            float sum = 0.f;
            const int mm = (t >> 2) + 1;
            for (int m = 0; m < mm; ++m) {
                const int s = g + 4 * m;
                sum += As[t][s] * Ts[s][j];
            }
            sum = dpp_xadd<0xB1>(sum);
            sum = dpp_xadd<0x4E>(sum);
            if (g == 0) Ts[t][j] = ((t == j) ? 1.f : 0.f) - sum;
        }
    }
    __syncthreads();

    // store T (bf16 row-major [t][s])
    {
        const int t = tid >> 2, s0 = (tid & 3) * 16;
        ushort8 o0, o1;
#pragma unroll
        for (int u = 0; u < 8; ++u) {
            o0[u] = f2b(Ts[t][s0 + u]);
            o1[u] = f2b(Ts[t][s0 + 8 + u]);
        }
        *(ushort8*)&Tc[t * 64 + s0]     = o0;
        *(ushort8*)&Tc[t * 64 + s0 + 8] = o1;
    }
    // store Kt (bf16 [j][t])
    {
        const int j = tid & 63, t0 = (tid >> 6) * 16;
        ushort8 o0, o1;
#pragma unroll
        for (int u = 0; u < 8; ++u) {
            o0[u] = kc[(t0 + u) * 64 + j];
            o1[u] = kc[(t0 + 8 + u) * 64 + j];
        }
        *(ushort8*)&Ktc[j * 64 + t0]     = o0;
        *(ushort8*)&Ktc[j * 64 + t0 + 8] = o1;
    }
}

// ---------------------------------------------------------------------------
// Kernel 3 (phase 2, sequential): one block per chain. Per chunk:
//   Btn = lr*(V^T - W K^T); Etn = Btn T^T; W += Etn Kt^T;
//   Out = Q W^T + S Etn^T -> hidden (off critical path, after W-update).
// NEW (r6): all six operand tiles (q,k,v,T,S,Kt) for chunk c+1 are staged
// into double-buffered LDS via global_load_lds (pre-swizzled source, linear
// dest) at the TOP of chunk c's compute; one vmcnt(0) at iteration end.
// HBM latency is thus hidden under ~2000cy of compute instead of being
// serially exposed every chunk (round-5 cost: ~8160 cy/chunk).
// ---------------------------------------------------------------------------
__global__ __launch_bounds__(256, 1) void ttt_chunk_kernel(
    const u16* __restrict__ qb, const u16* __restrict__ kb,
    const u16* __restrict__ vb,
    const u16* __restrict__ Tg, const u16* __restrict__ Sg,
    const u16* __restrict__ Ktg,
    const float* __restrict__ lr_scale, u16* __restrict__ hid)
{
    const int bh = blockIdx.x;
    const int b = bh / HH, h = bh % HH;
    const float lr = 0.01f * lr_scale[h];
    const int tid = threadIdx.x, lane = tid & 63, wid = tid >> 6;
    const int wm = (wid >> 1) * 32, wn = (wid & 1) * 32;
    const int ar0 = wm + (lane & 15);
    const int br0 = wn + (lane & 15);
    const int lcb = lane >> 4;
    const int or0 = wm + ((lane >> 4) << 2);
    const int oc0 = wn + (lane & 15);

    // staged operand tiles: [buf][tensor][64*64]; q=0,k=1,v=2,T=3,S=4,Kt=5
    __shared__ u16 stage[2][6 * 64 * 64];     // 96 KB
    __shared__ u16 Wb[64 * 64];               // 8 KB
    __shared__ u16 Btn[64 * 64];
    __shared__ u16 Etn[64 * 64];

    f32x4 accW[2][2];
#pragma unroll
    for (int a = 0; a < 2; ++a)
#pragma unroll
        for (int c = 0; c < 2; ++c) accW[a][c] = (f32x4){0.f, 0.f, 0.f, 0.f};

    const u16* qch = qb + (size_t)bh * TT * DD;
    const u16* kch = kb + (size_t)bh * TT * DD;
    const u16* vch = vb + (size_t)bh * TT * DD;
    const u16* Tch = Tg + (size_t)bh * NCH * (CL * CL);
    const u16* Sch = Sg + (size_t)bh * NCH * (CL * CL);
    const u16* Kth = Ktg + (size_t)bh * NCH * (CL * CL);
    u16* hch = hid + (size_t)b * TT * CC + h * DD;

    // stage chunk cn's 6 tiles into stage[pb] (12 gload16/thread, no wait)
    auto issue_stage = [&](int pb, int cn) {
        const u16* srcs[6] = {
            qch + (size_t)cn * (CL * DD), kch + (size_t)cn * (CL * DD),
            vch + (size_t)cn * (CL * DD), Tch + (size_t)cn * (CL * CL),
            Sch + (size_t)cn * (CL * CL), Kth + (size_t)cn * (CL * CL)};
#pragma unroll
        for (int j = 0; j < 6; ++j)
#pragma unroll
            for (int i = 0; i < 2; ++i) {
                int slot = i * 256 + tid;
                int row = slot >> 3, cc = slot & 7;
                int gc = cc ^ (row & 7);
                GLOAD16(srcs[j] + row * 64 + gc * 8,
                        (char*)&stage[pb][j * 4096] + slot * 16);
            }
    };

    issue_stage(0, 0);
    asm volatile("s_waitcnt vmcnt(0)" ::: "memory");
    __syncthreads();

#pragma unroll 1
    for (int c = 0; c < NCH; ++c) {
        const int p = c & 1;
        const u16* Sq  = &stage[p][0 * 4096];
        const u16* Sk  = &stage[p][1 * 4096];
        const u16* Sv  = &stage[p][2 * 4096];
        const u16* St  = &stage[p][3 * 4096];
        const u16* Ss  = &stage[p][4 * 4096];
        const u16* Skt = &stage[p][5 * 4096];

        // prefetch next chunk into the other buffer (flies under compute)
        if (c + 1 < NCH) issue_stage(p ^ 1, c + 1);

        // ---- W -> bf16 LDS (swizzled) ----
#pragma unroll
        for (int mi = 0; mi < 2; ++mi)
#pragma unroll
            for (int ni = 0; ni < 2; ++ni)
#pragma unroll
                for (int r = 0; r < 4; ++r)
                    st_sw(Wb, or0 + mi * 16 + r, oc0 + ni * 16,
                          f2b(accW[mi][ni][r]));
        __syncthreads();                                   // b1

        // ---- gemm1: (W K^T)[i,s]; Btn = lr*(V^T - .) ----
        uint2 vfr[2][2];
#pragma unroll
        for (int mi = 0; mi < 2; ++mi)
#pragma unroll
            for (int ni = 0; ni < 2; ++ni)
                vfr[mi][ni] = ld_v8(Sv, oc0 + ni * 16, or0 + mi * 16);

        f32x4 a1[2][2];
#pragma unroll
        for (int a = 0; a < 2; ++a)
#pragma unroll
            for (int d = 0; d < 2; ++d) a1[a][d] = (f32x4){0.f, 0.f, 0.f, 0.f};
#pragma unroll
        for (int kh = 0; kh < 2; ++kh) {
            short8 wf[2], Kf[2];
#pragma unroll
            for (int mi = 0; mi < 2; ++mi) {
                wf[mi] = ld_frag(Wb, ar0 + mi * 16, kh * 4 + lcb);
                Kf[mi] = ld_frag(Sk, br0 + mi * 16, kh * 4 + lcb);
            }
#pragma unroll
            for (int mi = 0; mi < 2; ++mi)
#pragma unroll
                for (int ni = 0; ni < 2; ++ni)
                    a1[mi][ni] = __builtin_amdgcn_mfma_f32_16x16x32_bf16(
                        wf[mi], Kf[ni], a1[mi][ni], 0, 0, 0);
        }
#pragma unroll
        for (int mi = 0; mi < 2; ++mi)
#pragma unroll
            for (int ni = 0; ni < 2; ++ni) {
                unsigned int lo = vfr[mi][ni].x, hi = vfr[mi][ni].y;
                u16 ve[4] = {(u16)(lo & 0xFFFF), (u16)(lo >> 16),
                             (u16)(hi & 0xFFFF), (u16)(hi >> 16)};
#pragma unroll
                for (int r = 0; r < 4; ++r) {
                    float val = lr * (b2f(ve[r]) - a1[mi][ni][r]);
                    st_sw(Btn, or0 + mi * 16 + r, oc0 + ni * 16, f2b(val));
                }
            }
        __syncthreads();                                   // b2

        // ---- gemm2: Etn[i,t] = Btn T^T ----
        f32x4 a2[2][2];
#pragma unroll
        for (int a = 0; a < 2; ++a)
#pragma unroll
            for (int d = 0; d < 2; ++d) a2[a][d] = (f32x4){0.f, 0.f, 0.f, 0.f};
#pragma unroll
        for (int kh = 0; kh < 2; ++kh) {
            short8 bt[2], Tf[2];
#pragma unroll
            for (int mi = 0; mi < 2; ++mi) {
                bt[mi] = ld_frag(Btn, ar0 + mi * 16, kh * 4 + lcb);
                Tf[mi] = ld_frag(St,  br0 + mi * 16, kh * 4 + lcb);
            }
#pragma unroll
            for (int mi = 0; mi < 2; ++mi)
#pragma unroll
                for (int ni = 0; ni < 2; ++ni)
                    a2[mi][ni] = __builtin_amdgcn_mfma_f32_16x16x32_bf16(
                        bt[mi], Tf[ni], a2[mi][ni], 0, 0, 0);
        }
#pragma unroll
        for (int mi = 0; mi < 2; ++mi)
#pragma unroll
            for (int ni = 0; ni < 2; ++ni)
#pragma unroll
                for (int r = 0; r < 4; ++r)
                    st_sw(Etn, or0 + mi * 16 + r, oc0 + ni * 16,
                          f2b(a2[mi][ni][r]));
        __syncthreads();                                   // b3

        // ---- gemm5 (critical path first): W += Etn Kt^T ----
#pragma unroll
        for (int kh = 0; kh < 2; ++kh) {
            short8 eta[2], Ktf[2];
#pragma unroll
            for (int mi = 0; mi < 2; ++mi) {
                eta[mi] = ld_frag(Etn, ar0 + mi * 16, kh * 4 + lcb);
                Ktf[mi] = ld_frag(Skt, br0 + mi * 16, kh * 4 + lcb);
            }
#pragma unroll
            for (int mi = 0; mi < 2; ++mi)
#pragma unroll
                for (int ni = 0; ni < 2; ++ni)
                    accW[mi][ni] = __builtin_amdgcn_mfma_f32_16x16x32_bf16(
                        eta[mi], Ktf[ni], accW[mi][ni], 0, 0, 0);
        }

        // ---- gemm3 (off path): Out[t,i] = Q W^T + S Etn^T -> hidden ----
        f32x4 a3[2][2];
#pragma unroll
        for (int a = 0; a < 2; ++a)
#pragma unroll
            for (int d = 0; d < 2; ++d) a3[a][d] = (f32x4){0.f, 0.f, 0.f, 0.f};
#pragma unroll
        for (int kh = 0; kh < 2; ++kh) {
            short8 Qf[2], Sf[2], wbf[2], etb[2];
#pragma unroll
            for (int i = 0; i < 2; ++i) {
                Qf[i]  = ld_frag(Sq,  ar0 + i * 16, kh * 4 + lcb);
                Sf[i]  = ld_frag(Ss,  ar0 + i * 16, kh * 4 + lcb);
                wbf[i] = ld_frag(Wb,  br0 + i * 16, kh * 4 + lcb);
                etb[i] = ld_frag(Etn, br0 + i * 16, kh * 4 + lcb);
            }
#pragma unroll
            for (int mi = 0; mi < 2; ++mi)
#pragma unroll
                for (int ni = 0; ni < 2; ++ni) {
                    a3[mi][ni] = __builtin_amdgcn_mfma_f32_16x16x32_bf16(
                        Qf[mi], wbf[ni], a3[mi][ni], 0, 0, 0);
                    a3[mi][ni] = __builtin_amdgcn_mfma_f32_16x16x32_bf16(
                        Sf[mi], etb[ni], a3[mi][ni], 0, 0, 0);
                }
        }
#pragma unroll
        for (int mi = 0; mi < 2; ++mi)
#pragma unroll
            for (int ni = 0; ni < 2; ++ni)
#pragma unroll
                for (int r = 0; r < 4; ++r)
                    hch[(size_t)(c * CL + or0 + mi * 16 + r) * CC
                        + oc0 + ni * 16] = f2b(a3[mi][ni][r]);

        // next-chunk staging (and hidden stores) complete before buffer swap
        asm volatile("s_waitcnt vmcnt(0)" ::: "memory");
        __syncthreads();                                   // b4
    }
}

// ---------------------------------------------------------------------------
// Kernel 4: output projection (bf16 MFMA, fp32 row-major out).
// ---------------------------------------------------------------------------
__global__ __launch_bounds__(256) void out_proj_kernel(
    const u16* __restrict__ hid, const u16* __restrict__ wo,
    float* __restrict__ out)
{
    const int m0 = blockIdx.x * 128;
    const int n0 = blockIdx.y * 128;
    const int tid = threadIdx.x, lane = tid & 63, wid = tid >> 6;
    const int wm = (wid >> 1) * 64, wn = (wid & 1) * 64;

    __shared__ u16 As[128 * 64];
    __shared__ u16 Bs[128 * 64];

    f32x4 acc[4][4];
#pragma unroll
    for (int a = 0; a < 4; ++a)
#pragma unroll
        for (int b = 0; b < 4; ++b) acc[a][b] = (f32x4){0.f, 0.f, 0.f, 0.f};

    for (int kt = 0; kt < CC; kt += 64) {
#pragma unroll
        for (int i = 0; i < 4; ++i) {
            int slot = i * 256 + tid;
            int row = slot >> 3, c = slot & 7;
            int gc = c ^ (row & 7);
            GLOAD16(hid + (size_t)(m0 + row) * CC + kt + gc * 8,
                    (char*)As + slot * 16);
            GLOAD16(wo  + (size_t)(n0 + row) * CC + kt + gc * 8,
                    (char*)Bs + slot * 16);
        }
        asm volatile("s_waitcnt vmcnt(0)" ::: "memory");
        __syncthreads();

#pragma unroll
        for (int kh = 0; kh < 2; ++kh) {
            short8 af[4], bf[4];
            const int lc = kh * 4 + (lane >> 4);
#pragma unroll
            for (int mi = 0; mi < 4; ++mi) {
                int row = wm + mi * 16 + (lane & 15);
                af[mi] = *(const short8*)((const char*)As + row * 128
                                          + ((lc ^ (row & 7)) * 16));
            }
#pragma unroll
            for (int ni = 0; ni < 4; ++ni) {
                int row = wn + ni * 16 + (lane & 15);
                bf[ni] = *(const short8*)((const char*)Bs + row * 128
                                          + ((lc ^ (row & 7)) * 16));
            }
#pragma unroll
            for (int mi = 0; mi < 4; ++mi)
#pragma unroll
                for (int ni = 0; ni < 4; ++ni)
                    acc[mi][ni] = __builtin_amdgcn_mfma_f32_16x16x32_bf16(
                        af[mi], bf[ni], acc[mi][ni], 0, 0, 0);
        }
        __syncthreads();
    }

#pragma unroll
    for (int mi = 0; mi < 4; ++mi) {
#pragma unroll
        for (int ni = 0; ni < 4; ++ni) {
            int n = n0 + wn + ni * 16 + (lane & 15);
            int mbase = m0 + wm + mi * 16 + ((lane >> 4) << 2);
#pragma unroll
            for (int r = 0; r < 4; ++r)
                out[(size_t)(mbase + r) * CC + n] = acc[mi][ni][r];
        }
    }
}

// ---------------------------------------------------------------------------
extern "C" void kernel_launch(void* const* d_in, const int* in_sizes, int n_in,
                              void* d_out, int out_size, void* d_ws, size_t ws_size,
                              hipStream_t stream) {
    const float* x  = (const float*)d_in[0];
    const float* Wq = (const float*)d_in[1];
    const float* Wk = (const float*)d_in[2];
    const float* Wv = (const float*)d_in[3];
    const float* Wo = (const float*)d_in[4];
    const float* lr = (const float*)d_in[5];

    // workspace layout (all bf16): 7*NQ + 4*WSZ ushorts = 48.8 MB
    u16* us  = (u16*)d_ws;
    u16* qb  = us;
    u16* kbw = us + (size_t)NQ;
    u16* vbw = us + (size_t)2 * NQ;
    u16* xb  = us + (size_t)3 * NQ;   // reused as hidden after proj
    u16* Tg  = us + (size_t)4 * NQ;
    u16* Sg  = us + (size_t)5 * NQ;
    u16* Ktg = us + (size_t)6 * NQ;
    u16* wqb = us + (size_t)7 * NQ;
    u16* wkb = wqb + WSZ;
    u16* wvb = wkb + WSZ;
    u16* wob = wvb + WSZ;
    u16* hid = xb;

    // 0) fp32 -> bf16
    cvt5_kernel<<<dim3((NQ / 8 + 255) / 256, 5), 256, 0, stream>>>(
        x, Wq, Wk, Wv, Wo, xb, wqb, wkb, wvb, wob);

    // 1) q/k/v projections (bf16 out, [B,H,T,D])
    proj_qkv_kernel<<<dim3(NN / 128, CC / 128, 3), 256, 0, stream>>>(
        xb, wqb, wkb, wvb, qb, kbw, vbw);

    // 2) phase 1: per-chunk T, S, Kt (768 parallel blocks)
    ttt_prep_kernel<<<dim3(BB * HH * NCH), 256, 0, stream>>>(
        qb, kbw, lr, Tg, Sg, Ktg);

    // 3) phase 2: sequential chunk scan, 24 blocks (LDS-pipelined operands)
    ttt_chunk_kernel<<<dim3(BB * HH), 256, 0, stream>>>(
        qb, kbw, vbw, Tg, Sg, Ktg, lr, hid);

    // 4) output projection
    out_proj_kernel<<<dim3(NN / 128, CC / 128), 256, 0, stream>>>(
        hid, wob, (float*)d_out);
}

// Round 7
// 156.720 us; speedup vs baseline: 4.9235x; 1.0263x over previous
//
#include <hip/hip_runtime.h>

// Problem constants
#define BB 2
#define TT 2048
#define CC 768
#define HH 12
#define DD 64
#define NN (BB*TT)            // 4096 rows
#define NQ (BB*HH*TT*DD)      // 3145728 elements per q/k/v tensor
#define WSZ (CC*CC)           // 589824 per weight
#define NCH 32                // chunks per chain
#define CL 64                 // chunk length (timesteps)
#define NCHUNKS (BB*HH*NCH)   // 768 total chunks

typedef __attribute__((ext_vector_type(8))) short short8;
typedef __attribute__((ext_vector_type(8))) unsigned short ushort8;
typedef __attribute__((ext_vector_type(4))) float f32x4;
typedef unsigned short u16;

// async global->LDS: 16B per lane, dest = uniform wave base + lane*16
#define GLOAD16(g, l)                                                        \
    __builtin_amdgcn_global_load_lds(                                        \
        (const __attribute__((address_space(1))) void*)(g),                  \
        (__attribute__((address_space(3))) void*)(l), 16, 0, 0)

__device__ __forceinline__ u16 f2b(float f) {
    unsigned int u = __builtin_bit_cast(unsigned int, f);
    unsigned int r = (u + 0x7FFFu + ((u >> 16) & 1u)) >> 16;
    return (u16)r;
}
__device__ __forceinline__ float b2f(u16 b) {
    unsigned int u = ((unsigned int)b) << 16;
    return __builtin_bit_cast(float, u);
}
// VALU-speed cross-lane add via DPP quad_perm. 0xB1=xor1, 0x4E=xor2.
template <int CTRL>
__device__ __forceinline__ float dpp_xadd(float x) {
    int y = __builtin_amdgcn_update_dpp(0, __builtin_bit_cast(int, x),
                                        CTRL, 0xF, 0xF, true);
    return x + __builtin_bit_cast(float, y);
}
// Swizzled LDS helpers for [64][64] bf16 row-major tiles (128B rows split in
// 8 x 16B chunks, phys_chunk = chunk ^ (row&7)) -> conflict-free ds_read_b128.
__device__ __forceinline__ void st_sw(u16* buf, int row, int col, u16 v) {
    buf[row * 64 + ((((col >> 3) ^ (row & 7)) << 3) | (col & 7))] = v;
}
__device__ __forceinline__ u16 ld_sw(const u16* buf, int row, int col) {
    return buf[row * 64 + ((((col >> 3) ^ (row & 7)) << 3) | (col & 7))];
}
__device__ __forceinline__ short8 ld_frag(const u16* buf, int row, int lc) {
    return *(const short8*)&buf[row * 64 + ((lc ^ (row & 7)) << 3)];
}
// plain row-major global fragment (row of 64 bf16, 16B chunk lc)
__device__ __forceinline__ short8 gfrag(const u16* base, int row, int lc) {
    return *(const short8*)&base[row * 64 + lc * 8];
}

// ---------------------------------------------------------------------------
// Kernel 0: fp32 -> bf16 for x, Wq, Wk, Wv, Wo.
// ---------------------------------------------------------------------------
__global__ __launch_bounds__(256) void cvt5_kernel(
    const float* __restrict__ x,  const float* __restrict__ Wq,
    const float* __restrict__ Wk, const float* __restrict__ Wv,
    const float* __restrict__ Wo,
    u16* __restrict__ xb, u16* __restrict__ wqb, u16* __restrict__ wkb,
    u16* __restrict__ wvb, u16* __restrict__ wob)
{
    const int seg = blockIdx.y;
    const float* s; u16* d; int n8;
    if      (seg == 0) { s = x;  d = xb;  n8 = NQ  / 8; }
    else if (seg == 1) { s = Wq; d = wqb; n8 = WSZ / 8; }
    else if (seg == 2) { s = Wk; d = wkb; n8 = WSZ / 8; }
    else if (seg == 3) { s = Wv; d = wvb; n8 = WSZ / 8; }
    else               { s = Wo; d = wob; n8 = WSZ / 8; }
    int i = blockIdx.x * 256 + threadIdx.x;
    if (i >= n8) return;
    const float* p = s + (size_t)i * 8;
    ushort8 o;
#pragma unroll
    for (int j = 0; j < 8; ++j) o[j] = f2b(p[j]);
    *(ushort8*)(d + (size_t)i * 8) = o;
}

// ---------------------------------------------------------------------------
// Kernel 1: q/k/v projection, bf16 MFMA, bf16 output scattered to [B,H,T,D].
// ---------------------------------------------------------------------------
__global__ __launch_bounds__(256) void proj_qkv_kernel(
    const u16* __restrict__ xb,
    const u16* __restrict__ wq, const u16* __restrict__ wk,
    const u16* __restrict__ wv,
    u16* __restrict__ qo, u16* __restrict__ ko, u16* __restrict__ vo)
{
    const int z = blockIdx.z;
    const u16* Bsel = (z == 0) ? wq : ((z == 1) ? wk : wv);
    u16* Osel       = (z == 0) ? qo : ((z == 1) ? ko : vo);

    const int m0 = blockIdx.x * 128;
    const int n0 = blockIdx.y * 128;
    const int tid = threadIdx.x, lane = tid & 63, wid = tid >> 6;
    const int wm = (wid >> 1) * 64, wn = (wid & 1) * 64;

    __shared__ u16 As[128 * 64];
    __shared__ u16 Bs[128 * 64];

    f32x4 acc[4][4];
#pragma unroll
    for (int a = 0; a < 4; ++a)
#pragma unroll
        for (int b = 0; b < 4; ++b) acc[a][b] = (f32x4){0.f, 0.f, 0.f, 0.f};

    for (int kt = 0; kt < CC; kt += 64) {
#pragma unroll
        for (int i = 0; i < 4; ++i) {
            int slot = i * 256 + tid;
            int row = slot >> 3, c = slot & 7;
            int gc = c ^ (row & 7);
            GLOAD16(xb   + (size_t)(m0 + row) * CC + kt + gc * 8,
                    (char*)As + slot * 16);
            GLOAD16(Bsel + (size_t)(n0 + row) * CC + kt + gc * 8,
                    (char*)Bs + slot * 16);
        }
        asm volatile("s_waitcnt vmcnt(0)" ::: "memory");
        __syncthreads();

#pragma unroll
        for (int kh = 0; kh < 2; ++kh) {
            short8 af[4], bf[4];
            const int lc = kh * 4 + (lane >> 4);
#pragma unroll
            for (int mi = 0; mi < 4; ++mi) {
                int row = wm + mi * 16 + (lane & 15);
                af[mi] = *(const short8*)((const char*)As + row * 128
                                          + ((lc ^ (row & 7)) * 16));
            }
#pragma unroll
            for (int ni = 0; ni < 4; ++ni) {
                int row = wn + ni * 16 + (lane & 15);
                bf[ni] = *(const short8*)((const char*)Bs + row * 128
                                          + ((lc ^ (row & 7)) * 16));
            }
#pragma unroll
            for (int mi = 0; mi < 4; ++mi)
#pragma unroll
                for (int ni = 0; ni < 4; ++ni)
                    acc[mi][ni] = __builtin_amdgcn_mfma_f32_16x16x32_bf16(
                        af[mi], bf[ni], acc[mi][ni], 0, 0, 0);
        }
        __syncthreads();
    }

#pragma unroll
    for (int mi = 0; mi < 4; ++mi) {
#pragma unroll
        for (int ni = 0; ni < 4; ++ni) {
            int n = n0 + wn + ni * 16 + (lane & 15);
            int mbase = m0 + wm + mi * 16 + ((lane >> 4) << 2);
            int h = n >> 6, d = n & 63;
#pragma unroll
            for (int r = 0; r < 4; ++r) {
                int m = mbase + r;
                int b = m >> 11, t = m & 2047;
                Osel[(((size_t)b * HH + h) * TT + t) * DD + d] =
                    f2b(acc[mi][ni][r]);
            }
        }
    }
}

// ---------------------------------------------------------------------------
// Kernel 2 (prep, parallel over 768 chunks): per chunk
//   A = lr*stril(K K^T); T = (I+A)^{-1} (solve);
//   R = lr*(K^T T^T) [j,t]; U = lr*(V^T T^T) [i,t]; Rtn[t,j] = -R[j,t];
//   Mtn = -(R K)^T (bf16, B-frag-major -> global);
//   P = U K (fp32, C-frag-major -> global);  U (bf16, C-frag-major -> global).
// All W-dependence removed from the sequential chain.
// ---------------------------------------------------------------------------
__global__ __launch_bounds__(256) void ttt_prep2_kernel(
    const u16* __restrict__ kb, const u16* __restrict__ vb,
    const float* __restrict__ lr_scale,
    u16* __restrict__ ubg, float* __restrict__ pfA, float* __restrict__ pfB,
    u16* __restrict__ mtng, u16* __restrict__ rtng)
{
    const int bx = blockIdx.x;
    const int bh = bx >> 5;
    const int h = bh % HH;
    const float lr = 0.01f * lr_scale[h];
    const u16* kc = kb + (size_t)bx * 4096;
    const u16* vc = vb + (size_t)bx * 4096;
    u16* ubc  = ubg + (size_t)bx * 4096;
    float* pfc = (bx < 384) ? pfA + (size_t)bx * 4096
                            : pfB + (size_t)(bx - 384) * 4096;
    u16* mtnc = mtng + (size_t)bx * 4096;
    u16* rtnc = rtng + (size_t)bx * 4096;

    const int tid = threadIdx.x, lane = tid & 63, wid = tid >> 6;
    const int wm = (wid >> 1) * 32, wn = (wid & 1) * 32;
    const int ar0 = wm + (lane & 15);
    const int br0 = wn + (lane & 15);
    const int lcb = lane >> 4;
    const int or0 = wm + ((lane >> 4) << 2);
    const int oc0 = wn + (lane & 15);

    __shared__ u16 Kl[4096], Vl[4096];
    __shared__ float As[64][68];
    __shared__ float Ts[64][68];
    __shared__ u16 KtB[4096], VtB[4096], Tb[4096], Rb[4096], Ub[4096];
    __shared__ u16 TmpA[4096], TmpB[4096];

    // stage K,V (source pre-swizzled, linear LDS dest)
#pragma unroll
    for (int i = 0; i < 2; ++i) {
        int slot = i * 256 + tid;
        int row = slot >> 3, cc = slot & 7;
        int gc = cc ^ (row & 7);
        GLOAD16(kc + row * 64 + gc * 8, (char*)Kl + slot * 16);
        GLOAD16(vc + row * 64 + gc * 8, (char*)Vl + slot * 16);
    }
    asm volatile("s_waitcnt vmcnt(0)" ::: "memory");
    __syncthreads();

    // aA = K K^T
    f32x4 aA[2][2];
#pragma unroll
    for (int a = 0; a < 2; ++a)
#pragma unroll
        for (int b = 0; b < 2; ++b) aA[a][b] = (f32x4){0.f, 0.f, 0.f, 0.f};
#pragma unroll
    for (int kh = 0; kh < 2; ++kh) {
        short8 ka[2], kbb[2];
#pragma unroll
        for (int i = 0; i < 2; ++i) {
            ka[i]  = ld_frag(Kl, ar0 + i * 16, kh * 4 + lcb);
            kbb[i] = ld_frag(Kl, br0 + i * 16, kh * 4 + lcb);
        }
#pragma unroll
        for (int mi = 0; mi < 2; ++mi)
#pragma unroll
            for (int ni = 0; ni < 2; ++ni)
                aA[mi][ni] = __builtin_amdgcn_mfma_f32_16x16x32_bf16(
                    ka[mi], kbb[ni], aA[mi][ni], 0, 0, 0);
    }
#pragma unroll
    for (int mi = 0; mi < 2; ++mi)
#pragma unroll
        for (int ni = 0; ni < 2; ++ni)
#pragma unroll
            for (int r = 0; r < 4; ++r) {
                int t = or0 + mi * 16 + r, s = oc0 + ni * 16;
                As[t][s] = (t > s) ? lr * aA[mi][ni][r] : 0.f;
            }
    // build Kt, Vt via LDS->LDS transpose
    {
        const int j = tid >> 2, t0 = (tid & 3) * 16;
#pragma unroll
        for (int u = 0; u < 16; ++u) {
            st_sw(KtB, j, t0 + u, ld_sw(Kl, t0 + u, j));
            st_sw(VtB, j, t0 + u, ld_sw(Vl, t0 + u, j));
        }
    }
    // zero Ts
    for (int i = tid; i < 64 * 68; i += 256) (&Ts[0][0])[i] = 0.f;
    __syncthreads();                                            // B1

    // forward substitution: T[t][j] = delta(t,j) - sum_{s<t} A[t][s] T[s][j]
    {
        const int j = wid * 16 + (lane >> 2), g = lane & 3;
        for (int t = 0; t < 64; ++t) {
            float sum = 0.f;
            const int mm = (t >> 2) + 1;
            for (int m = 0; m < mm; ++m) {
                const int s = g + 4 * m;
                sum += As[t][s] * Ts[s][j];
            }
            sum = dpp_xadd<0xB1>(sum);
            sum = dpp_xadd<0x4E>(sum);
            if (g == 0) Ts[t][j] = ((t == j) ? 1.f : 0.f) - sum;
        }
    }
    __syncthreads();                                            // B2
    // Tb = bf16(Ts)
    {
        const int t = tid >> 2, s0 = (tid & 3) * 16;
#pragma unroll
        for (int u = 0; u < 16; ++u) st_sw(Tb, t, s0 + u, f2b(Ts[t][s0 + u]));
    }
    __syncthreads();                                            // B3

    // R = lr*mfma(Kt,T); U = lr*mfma(Vt,T); Rtn = -lr*mfma(T,Kt)
    f32x4 aR[2][2], aU[2][2], aRt[2][2];
#pragma unroll
    for (int a = 0; a < 2; ++a)
#pragma unroll
        for (int b = 0; b < 2; ++b) {
            aR[a][b] = (f32x4){0.f, 0.f, 0.f, 0.f};
            aU[a][b] = (f32x4){0.f, 0.f, 0.f, 0.f};
            aRt[a][b] = (f32x4){0.f, 0.f, 0.f, 0.f};
        }
#pragma unroll
    for (int kh = 0; kh < 2; ++kh) {
        short8 kta[2], vta[2], ta[2], tbf[2], ktb[2];
#pragma unroll
        for (int i = 0; i < 2; ++i) {
            kta[i] = ld_frag(KtB, ar0 + i * 16, kh * 4 + lcb);
            vta[i] = ld_frag(VtB, ar0 + i * 16, kh * 4 + lcb);
            ta[i]  = ld_frag(Tb,  ar0 + i * 16, kh * 4 + lcb);
            tbf[i] = ld_frag(Tb,  br0 + i * 16, kh * 4 + lcb);
            ktb[i] = ld_frag(KtB, br0 + i * 16, kh * 4 + lcb);
        }
#pragma unroll
        for (int mi = 0; mi < 2; ++mi)
#pragma unroll
            for (int ni = 0; ni < 2; ++ni) {
                aR[mi][ni] = __builtin_amdgcn_mfma_f32_16x16x32_bf16(
                    kta[mi], tbf[ni], aR[mi][ni], 0, 0, 0);
                aU[mi][ni] = __builtin_amdgcn_mfma_f32_16x16x32_bf16(
                    vta[mi], tbf[ni], aU[mi][ni], 0, 0, 0);
                aRt[mi][ni] = __builtin_amdgcn_mfma_f32_16x16x32_bf16(
                    ta[mi], ktb[ni], aRt[mi][ni], 0, 0, 0);
            }
    }
#pragma unroll
    for (int mi = 0; mi < 2; ++mi)
#pragma unroll
        for (int ni = 0; ni < 2; ++ni) {
            // Ub global store (C-frag-major bf16) + LDS copies
            u16 ue[4];
#pragma unroll
            for (int r = 0; r < 4; ++r) {
                int ro = or0 + mi * 16 + r, co = oc0 + ni * 16;
                st_sw(Rb, ro, co, f2b(lr * aR[mi][ni][r]));
                ue[r] = f2b(lr * aU[mi][ni][r]);
                st_sw(Ub, ro, co, ue[r]);
                st_sw(TmpA, ro, co, f2b(-lr * aRt[mi][ni][r]));
            }
            uint2 uo;
            uo.x = (unsigned)ue[0] | ((unsigned)ue[1] << 16);
            uo.y = (unsigned)ue[2] | ((unsigned)ue[3] << 16);
            *(uint2*)&ubc[(size_t)((((wid * 2 + mi) * 2 + ni) * 64 + lane) * 4)] = uo;
        }
    __syncthreads();                                            // B4

    // Mtn = -mfma(Kt, R) -> TmpB ;  P = mfma(U, Kt) -> pfc (fp32 C-frag)
    f32x4 aM[2][2], aP[2][2];
#pragma unroll
    for (int a = 0; a < 2; ++a)
#pragma unroll
        for (int b = 0; b < 2; ++b) {
            aM[a][b] = (f32x4){0.f, 0.f, 0.f, 0.f};
            aP[a][b] = (f32x4){0.f, 0.f, 0.f, 0.f};
        }
#pragma unroll
    for (int kh = 0; kh < 2; ++kh) {
        short8 kta[2], ua[2], rbb[2], ktb[2];
#pragma unroll
        for (int i = 0; i < 2; ++i) {
            kta[i] = ld_frag(KtB, ar0 + i * 16, kh * 4 + lcb);
            ua[i]  = ld_frag(Ub,  ar0 + i * 16, kh * 4 + lcb);
            rbb[i] = ld_frag(Rb,  br0 + i * 16, kh * 4 + lcb);
            ktb[i] = ld_frag(KtB, br0 + i * 16, kh * 4 + lcb);
        }
#pragma unroll
        for (int mi = 0; mi < 2; ++mi)
#pragma unroll
            for (int ni = 0; ni < 2; ++ni) {
                aM[mi][ni] = __builtin_amdgcn_mfma_f32_16x16x32_bf16(
                    kta[mi], rbb[ni], aM[mi][ni], 0, 0, 0);
                aP[mi][ni] = __builtin_amdgcn_mfma_f32_16x16x32_bf16(
                    ua[mi], ktb[ni], aP[mi][ni], 0, 0, 0);
            }
    }
#pragma unroll
    for (int mi = 0; mi < 2; ++mi)
#pragma unroll
        for (int ni = 0; ni < 2; ++ni) {
#pragma unroll
            for (int r = 0; r < 4; ++r)
                st_sw(TmpB, or0 + mi * 16 + r, oc0 + ni * 16,
                      f2b(-aM[mi][ni][r]));
            *(f32x4*)&pfc[(size_t)((((wid * 2 + mi) * 2 + ni) * 64 + lane) * 4)]
                = aP[mi][ni];
        }
    // Rtn B-frag store (TmpA ready since B4)
    if (wid < 2) {
#pragma unroll
        for (int ni = 0; ni < 2; ++ni)
#pragma unroll
            for (int kh = 0; kh < 2; ++kh) {
                short8 v = ld_frag(TmpA, wid * 32 + ni * 16 + (lane & 15),
                                   kh * 4 + lcb);
                *(short8*)&rtnc[(size_t)((((wid * 2 + ni) * 2 + kh) * 64
                                          + lane) * 8)] = v;
            }
    }
    __syncthreads();                                            // B5
    if (wid < 2) {
#pragma unroll
        for (int ni = 0; ni < 2; ++ni)
#pragma unroll
            for (int kh = 0; kh < 2; ++kh) {
                short8 v = ld_frag(TmpB, wid * 32 + ni * 16 + (lane & 15),
                                   kh * 4 + lcb);
                *(short8*)&mtnc[(size_t)((((wid * 2 + ni) * 2 + kh) * 64
                                          + lane) * 8)] = v;
            }
    }
}

// ---------------------------------------------------------------------------
// Kernel 3 (seq): one block per chain; per chunk the ONLY serial work is
//   store W_c (bf16, row-major -> global  [aliased over consumed Mtn])
//   Delta = P_c + W_c * Mtn_c   (acc-init P, 8 MFMA) ;  accW += Delta.
// Mtn/P for chunk c+1 reg-prefetched (named A/B sets); vmcnt(0) at body top
// guarantees the prefetch completed before W_c overwrites the Mtn region.
// ---------------------------------------------------------------------------
__global__ __launch_bounds__(256, 1) void ttt_seq_kernel(
    u16* __restrict__ mtnW, const float* __restrict__ pfA,
    const float* __restrict__ pfB)
{
    const int bh = blockIdx.x;
    const int bx0 = bh * NCH;
    const int tid = threadIdx.x, lane = tid & 63, wid = tid >> 6;
    const int wm = (wid >> 1) * 32, wn = (wid & 1) * 32;
    const int ar0 = wm + (lane & 15);
    const int lcb = lane >> 4;
    const int or0 = wm + ((lane >> 4) << 2);
    const int oc0 = wn + (lane & 15);
    const int wn2 = wid & 1;

    __shared__ u16 Wb[4096];

    f32x4 accW[2][2];
#pragma unroll
    for (int a = 0; a < 2; ++a)
#pragma unroll
        for (int b = 0; b < 2; ++b) accW[a][b] = (f32x4){0.f, 0.f, 0.f, 0.f};

    auto ldMtn = [&](int c, short8 (&m)[2][2]) {
        const u16* mb = mtnW + (size_t)(bx0 + c) * 4096;
#pragma unroll
        for (int ni = 0; ni < 2; ++ni)
#pragma unroll
            for (int kh = 0; kh < 2; ++kh)
                m[ni][kh] = *(const short8*)&mb[(size_t)(
                    (((wn2 * 2 + ni) * 2 + kh) * 64 + lane) * 8)];
    };
    auto ldPf = [&](int c, f32x4 (&p)[2][2]) {
        int bx = bx0 + c;
        const float* pb = (bx < 384) ? pfA + (size_t)bx * 4096
                                     : pfB + (size_t)(bx - 384) * 4096;
#pragma unroll
        for (int mi = 0; mi < 2; ++mi)
#pragma unroll
            for (int ni = 0; ni < 2; ++ni)
                p[mi][ni] = *(const f32x4*)&pb[(size_t)(
                    (((wid * 2 + mi) * 2 + ni) * 64 + lane) * 4)];
    };

    auto body = [&](int c, short8 (&cm)[2][2], f32x4 (&cp)[2][2],
                    short8 (&nm)[2][2], f32x4 (&np)[2][2]) {
        // drain prior prefetch: its region is about to be overwritten by W_c
        asm volatile("s_waitcnt vmcnt(0)" ::: "memory");
        u16* wcp = mtnW + (size_t)(bx0 + c) * 4096;
#pragma unroll
        for (int mi = 0; mi < 2; ++mi)
#pragma unroll
            for (int ni = 0; ni < 2; ++ni)
#pragma unroll
                for (int r = 0; r < 4; ++r) {
                    u16 v = f2b(accW[mi][ni][r]);
                    wcp[(or0 + mi * 16 + r) * 64 + oc0 + ni * 16] = v;
                    st_sw(Wb, or0 + mi * 16 + r, oc0 + ni * 16, v);
                }
        if (c + 1 < NCH) { ldMtn(c + 1, nm); ldPf(c + 1, np); }
        __syncthreads();
        short8 wf[2][2];
#pragma unroll
        for (int mi = 0; mi < 2; ++mi)
#pragma unroll
            for (int kh = 0; kh < 2; ++kh)
                wf[mi][kh] = ld_frag(Wb, ar0 + mi * 16, kh * 4 + lcb);
#pragma unroll
        for (int mi = 0; mi < 2; ++mi)
#pragma unroll
            for (int ni = 0; ni < 2; ++ni) {
                f32x4 d = cp[mi][ni];
#pragma unroll
                for (int kh = 0; kh < 2; ++kh)
                    d = __builtin_amdgcn_mfma_f32_16x16x32_bf16(
                        wf[mi][kh], cm[ni][kh], d, 0, 0, 0);
                accW[mi][ni] = accW[mi][ni] + d;
            }
        __syncthreads();
    };

    short8 mA[2][2], mB[2][2];
    f32x4 pA[2][2], pB[2][2];
    ldMtn(0, mA); ldPf(0, pA);
    for (int c = 0; c < NCH; c += 2) {
        body(c,     mA, pA, mB, pB);
        body(c + 1, mB, pB, mA, pA);
    }
}

// ---------------------------------------------------------------------------
// Kernel 4 (outgen, parallel over 768 chunks):
//   S = stril(Q K^T)  (recomputed, bit-identical inputs);
//   Etn = U + W * Rtn (acc-init U);  Out = Q W^T + S Etn^T -> hidden bf16.
// ---------------------------------------------------------------------------
__global__ __launch_bounds__(256) void ttt_outgen_kernel(
    const u16* __restrict__ qb, const u16* __restrict__ kb,
    const u16* __restrict__ wcg, const u16* __restrict__ rtng,
    const u16* __restrict__ ubg, u16* __restrict__ hid)
{
    const int bx = blockIdx.x;
    const int bh = bx >> 5, c = bx & 31;
    const int b = bh / HH, h = bh % HH;
    const u16* qc = qb + (size_t)bx * 4096;
    const u16* kc = kb + (size_t)bx * 4096;
    const u16* wcc = wcg + (size_t)bx * 4096;
    const u16* rtnc = rtng + (size_t)bx * 4096;
    const u16* ubc = ubg + (size_t)bx * 4096;
    u16* hch = hid + (size_t)b * TT * CC + h * DD;

    const int tid = threadIdx.x, lane = tid & 63, wid = tid >> 6;
    const int wm = (wid >> 1) * 32, wn = (wid & 1) * 32;
    const int ar0 = wm + (lane & 15);
    const int br0 = wn + (lane & 15);
    const int lcb = lane >> 4;
    const int or0 = wm + ((lane >> 4) << 2);
    const int oc0 = wn + (lane & 15);
    const int wn2 = wid & 1;

    __shared__ u16 Sl[4096], El[4096];

    // S = stril(Q K^T), direct global frags
    short8 Qa[2][2], Kb2[2][2];
#pragma unroll
    for (int i = 0; i < 2; ++i)
#pragma unroll
        for (int kh = 0; kh < 2; ++kh) {
            Qa[i][kh]  = gfrag(qc, ar0 + i * 16, kh * 4 + lcb);
            Kb2[i][kh] = gfrag(kc, br0 + i * 16, kh * 4 + lcb);
        }
    f32x4 aS[2][2];
#pragma unroll
    for (int a = 0; a < 2; ++a)
#pragma unroll
        for (int d = 0; d < 2; ++d) aS[a][d] = (f32x4){0.f, 0.f, 0.f, 0.f};
#pragma unroll
    for (int kh = 0; kh < 2; ++kh)
#pragma unroll
        for (int mi = 0; mi < 2; ++mi)
#pragma unroll
            for (int ni = 0; ni < 2; ++ni)
                aS[mi][ni] = __builtin_amdgcn_mfma_f32_16x16x32_bf16(
                    Qa[mi][kh], Kb2[ni][kh], aS[mi][ni], 0, 0, 0);
#pragma unroll
    for (int mi = 0; mi < 2; ++mi)
#pragma unroll
        for (int ni = 0; ni < 2; ++ni)
#pragma unroll
            for (int r = 0; r < 4; ++r) {
                int t = or0 + mi * 16 + r, s = oc0 + ni * 16;
                st_sw(Sl, t, s, f2b((t > s) ? aS[mi][ni][r] : 0.f));
            }

    // Etn = U + W * Rtn
    f32x4 aE[2][2];
#pragma unroll
    for (int mi = 0; mi < 2; ++mi)
#pragma unroll
        for (int ni = 0; ni < 2; ++ni) {
            uint2 uu = *(const uint2*)&ubc[(size_t)(
                (((wid * 2 + mi) * 2 + ni) * 64 + lane) * 4)];
            f32x4 e;
            e[0] = b2f((u16)(uu.x & 0xFFFF)); e[1] = b2f((u16)(uu.x >> 16));
            e[2] = b2f((u16)(uu.y & 0xFFFF)); e[3] = b2f((u16)(uu.y >> 16));
            aE[mi][ni] = e;
        }
    short8 Wa[2][2], Rtb[2][2];
#pragma unroll
    for (int i = 0; i < 2; ++i)
#pragma unroll
        for (int kh = 0; kh < 2; ++kh) {
            Wa[i][kh] = gfrag(wcc, ar0 + i * 16, kh * 4 + lcb);
            Rtb[i][kh] = *(const short8*)&rtnc[(size_t)(
                (((wn2 * 2 + i) * 2 + kh) * 64 + lane) * 8)];
        }
#pragma unroll
    for (int kh = 0; kh < 2; ++kh)
#pragma unroll
        for (int mi = 0; mi < 2; ++mi)
#pragma unroll
            for (int ni = 0; ni < 2; ++ni)
                aE[mi][ni] = __builtin_amdgcn_mfma_f32_16x16x32_bf16(
                    Wa[mi][kh], Rtb[ni][kh], aE[mi][ni], 0, 0, 0);
#pragma unroll
    for (int mi = 0; mi < 2; ++mi)
#pragma unroll
        for (int ni = 0; ni < 2; ++ni)
#pragma unroll
            for (int r = 0; r < 4; ++r)
                st_sw(El, or0 + mi * 16 + r, oc0 + ni * 16,
                      f2b(aE[mi][ni][r]));
    __syncthreads();

    // Out = Q W^T + S Etn^T
    f32x4 aO[2][2];
#pragma unroll
    for (int a = 0; a < 2; ++a)
#pragma unroll
        for (int d = 0; d < 2; ++d) aO[a][d] = (f32x4){0.f, 0.f, 0.f, 0.f};
#pragma unroll
    for (int kh = 0; kh < 2; ++kh) {
        short8 Wb2[2], Sa[2], Eb[2];
#pragma unroll
        for (int i = 0; i < 2; ++i) {
            Wb2[i] = gfrag(wcc, br0 + i * 16, kh * 4 + lcb);
            Sa[i]  = ld_frag(Sl, ar0 + i * 16, kh * 4 + lcb);
            Eb[i]  = ld_frag(El, br0 + i * 16, kh * 4 + lcb);
        }
#pragma unroll
        for (int mi = 0; mi < 2; ++mi)
#pragma unroll
            for (int ni = 0; ni < 2; ++ni) {
                aO[mi][ni] = __builtin_amdgcn_mfma_f32_16x16x32_bf16(
                    Qa[mi][kh], Wb2[ni], aO[mi][ni], 0, 0, 0);
                aO[mi][ni] = __builtin_amdgcn_mfma_f32_16x16x32_bf16(
                    Sa[mi], Eb[ni], aO[mi][ni], 0, 0, 0);
            }
    }
#pragma unroll
    for (int mi = 0; mi < 2; ++mi)
#pragma unroll
        for (int ni = 0; ni < 2; ++ni)
#pragma unroll
            for (int r = 0; r < 4; ++r)
                hch[(size_t)(c * CL + or0 + mi * 16 + r) * CC
                    + oc0 + ni * 16] = f2b(aO[mi][ni][r]);
}

// ---------------------------------------------------------------------------
// Kernel 5: output projection (bf16 MFMA, fp32 row-major out).
// ---------------------------------------------------------------------------
__global__ __launch_bounds__(256) void out_proj_kernel(
    const u16* __restrict__ hid, const u16* __restrict__ wo,
    float* __restrict__ out)
{
    const int m0 = blockIdx.x * 128;
    const int n0 = blockIdx.y * 128;
    const int tid = threadIdx.x, lane = tid & 63, wid = tid >> 6;
    const int wm = (wid >> 1) * 64, wn = (wid & 1) * 64;

    __shared__ u16 As[128 * 64];
    __shared__ u16 Bs[128 * 64];

    f32x4 acc[4][4];
#pragma unroll
    for (int a = 0; a < 4; ++a)
#pragma unroll
        for (int b = 0; b < 4; ++b) acc[a][b] = (f32x4){0.f, 0.f, 0.f, 0.f};

    for (int kt = 0; kt < CC; kt += 64) {
#pragma unroll
        for (int i = 0; i < 4; ++i) {
            int slot = i * 256 + tid;
            int row = slot >> 3, c = slot & 7;
            int gc = c ^ (row & 7);
            GLOAD16(hid + (size_t)(m0 + row) * CC + kt + gc * 8,
                    (char*)As + slot * 16);
            GLOAD16(wo  + (size_t)(n0 + row) * CC + kt + gc * 8,
                    (char*)Bs + slot * 16);
        }
        asm volatile("s_waitcnt vmcnt(0)" ::: "memory");
        __syncthreads();

#pragma unroll
        for (int kh = 0; kh < 2; ++kh) {
            short8 af[4], bf[4];
            const int lc = kh * 4 + (lane >> 4);
#pragma unroll
            for (int mi = 0; mi < 4; ++mi) {
                int row = wm + mi * 16 + (lane & 15);
                af[mi] = *(const short8*)((const char*)As + row * 128
                                          + ((lc ^ (row & 7)) * 16));
            }
#pragma unroll
            for (int ni = 0; ni < 4; ++ni) {
                int row = wn + ni * 16 + (lane & 15);
                bf[ni] = *(const short8*)((const char*)Bs + row * 128
                                          + ((lc ^ (row & 7)) * 16));
            }
#pragma unroll
            for (int mi = 0; mi < 4; ++mi)
#pragma unroll
                for (int ni = 0; ni < 4; ++ni)
                    acc[mi][ni] = __builtin_amdgcn_mfma_f32_16x16x32_bf16(
                        af[mi], bf[ni], acc[mi][ni], 0, 0, 0);
        }
        __syncthreads();
    }

#pragma unroll
    for (int mi = 0; mi < 4; ++mi) {
#pragma unroll
        for (int ni = 0; ni < 4; ++ni) {
            int n = n0 + wn + ni * 16 + (lane & 15);
            int mbase = m0 + wm + mi * 16 + ((lane >> 4) << 2);
#pragma unroll
            for (int r = 0; r < 4; ++r)
                out[(size_t)(mbase + r) * CC + n] = acc[mi][ni][r];
        }
    }
}

// ---------------------------------------------------------------------------
extern "C" void kernel_launch(void* const* d_in, const int* in_sizes, int n_in,
                              void* d_out, int out_size, void* d_ws, size_t ws_size,
                              hipStream_t stream) {
    const float* x  = (const float*)d_in[0];
    const float* Wq = (const float*)d_in[1];
    const float* Wk = (const float*)d_in[2];
    const float* Wv = (const float*)d_in[3];
    const float* Wo = (const float*)d_in[4];
    const float* lr = (const float*)d_in[5];

    // workspace: 7*NQ + 4*WSZ u16 (same proven size as round 6). Aliases:
    //  slot2: vb -> Ub      (per-chunk ranges coincide exactly)
    //  slot3: xb -> pfA(fp32) -> hid
    //  slot4: Mtn -> Wc     (seq consumes Mtn[c] before writing Wc[c])
    //  slot6: pfB (fp32 half of P)
    u16* us   = (u16*)d_ws;
    u16* qb   = us;
    u16* kbw  = us + (size_t)NQ;
    u16* vbw  = us + (size_t)2 * NQ;    // -> Ub
    u16* xb   = us + (size_t)3 * NQ;    // -> pfA -> hid
    u16* mtnW = us + (size_t)4 * NQ;    // -> Wc
    u16* rtn  = us + (size_t)5 * NQ;
    float* pfB = (float*)(us + (size_t)6 * NQ);
    u16* wqb = us + (size_t)7 * NQ;
    u16* wkb = wqb + WSZ;
    u16* wvb = wkb + WSZ;
    u16* wob = wvb + WSZ;
    u16* ub  = vbw;
    float* pfA = (float*)xb;
    u16* hid = xb;

    // 0) fp32 -> bf16
    cvt5_kernel<<<dim3((NQ / 8 + 255) / 256, 5), 256, 0, stream>>>(
        x, Wq, Wk, Wv, Wo, xb, wqb, wkb, wvb, wob);

    // 1) q/k/v projections (bf16 out, [B,H,T,D])
    proj_qkv_kernel<<<dim3(NN / 128, CC / 128, 3), 256, 0, stream>>>(
        xb, wqb, wkb, wvb, qb, kbw, vbw);

    // 2) prep: per-chunk U, P, Mtn, Rtn (768 parallel blocks)
    ttt_prep2_kernel<<<dim3(NCHUNKS), 256, 0, stream>>>(
        kbw, vbw, lr, ub, pfA, pfB, mtnW, rtn);

    // 3) seq: W-chain only, 24 blocks, 1 gemm per chunk
    ttt_seq_kernel<<<dim3(BB * HH), 256, 0, stream>>>(mtnW, pfA, pfB);

    // 4) outgen: per-chunk hidden output (768 parallel blocks)
    ttt_outgen_kernel<<<dim3(NCHUNKS), 256, 0, stream>>>(
        qb, kbw, mtnW, rtn, ub, hid);

    // 5) output projection
    out_proj_kernel<<<dim3(NN / 128, CC / 128), 256, 0, stream>>>(
        hid, wob, (float*)d_out);
}

// Round 8
// 103.505 us; speedup vs baseline: 7.4549x; 1.5141x over previous
//
#include <hip/hip_runtime.h>

// Problem constants
#define BB 2
#define TT 2048
#define CC 768
#define HH 12
#define DD 64
#define NN (BB*TT)            // 4096 rows
#define NQ (BB*HH*TT*DD)      // 3145728 elements per q/k/v tensor
#define WSZ (CC*CC)           // 589824 per weight
#define NCH 32                // chunks per chain
#define CL 64                 // chunk length (timesteps)
#define NCHUNKS (BB*HH*NCH)   // 768 total chunks

typedef __attribute__((ext_vector_type(8))) short short8;
typedef __attribute__((ext_vector_type(8))) unsigned short ushort8;
typedef __attribute__((ext_vector_type(4))) float f32x4;
typedef unsigned short u16;

// async global->LDS: 16B per lane, dest = uniform wave base + lane*16
#define GLOAD16(g, l)                                                        \
    __builtin_amdgcn_global_load_lds(                                        \
        (const __attribute__((address_space(1))) void*)(g),                  \
        (__attribute__((address_space(3))) void*)(l), 16, 0, 0)

__device__ __forceinline__ u16 f2b(float f) {
    unsigned int u = __builtin_bit_cast(unsigned int, f);
    unsigned int r = (u + 0x7FFFu + ((u >> 16) & 1u)) >> 16;
    return (u16)r;
}
__device__ __forceinline__ float b2f(u16 b) {
    unsigned int u = ((unsigned int)b) << 16;
    return __builtin_bit_cast(float, u);
}
// VALU-speed cross-lane add via DPP quad_perm. 0xB1=xor1, 0x4E=xor2.
// Butterfly: after both stages ALL 4 lanes of a quad hold the total.
template <int CTRL>
__device__ __forceinline__ float dpp_xadd(float x) {
    int y = __builtin_amdgcn_update_dpp(0, __builtin_bit_cast(int, x),
                                        CTRL, 0xF, 0xF, true);
    return x + __builtin_bit_cast(float, y);
}
// Swizzled LDS helpers for [64][64] bf16 row-major tiles (128B rows split in
// 8 x 16B chunks, phys_chunk = chunk ^ (row&7)) -> conflict-free ds_read_b128.
__device__ __forceinline__ void st_sw(u16* buf, int row, int col, u16 v) {
    buf[row * 64 + ((((col >> 3) ^ (row & 7)) << 3) | (col & 7))] = v;
}
__device__ __forceinline__ short8 ld_frag(const u16* buf, int row, int lc) {
    return *(const short8*)&buf[row * 64 + ((lc ^ (row & 7)) << 3)];
}
// plain row-major global fragment (row of 64 bf16, 16B chunk lc)
__device__ __forceinline__ short8 gfrag(const u16* base, int row, int lc) {
    return *(const short8*)&base[row * 64 + lc * 8];
}

// ---------------------------------------------------------------------------
// Kernel 0: fp32 -> bf16 for x, Wq, Wk, Wv, Wo.
// ---------------------------------------------------------------------------
__global__ __launch_bounds__(256) void cvt5_kernel(
    const float* __restrict__ x,  const float* __restrict__ Wq,
    const float* __restrict__ Wk, const float* __restrict__ Wv,
    const float* __restrict__ Wo,
    u16* __restrict__ xb, u16* __restrict__ wqb, u16* __restrict__ wkb,
    u16* __restrict__ wvb, u16* __restrict__ wob)
{
    const int seg = blockIdx.y;
    const float* s; u16* d; int n8;
    if      (seg == 0) { s = x;  d = xb;  n8 = NQ  / 8; }
    else if (seg == 1) { s = Wq; d = wqb; n8 = WSZ / 8; }
    else if (seg == 2) { s = Wk; d = wkb; n8 = WSZ / 8; }
    else if (seg == 3) { s = Wv; d = wvb; n8 = WSZ / 8; }
    else               { s = Wo; d = wob; n8 = WSZ / 8; }
    int i = blockIdx.x * 256 + threadIdx.x;
    if (i >= n8) return;
    const float* p = s + (size_t)i * 8;
    ushort8 o;
#pragma unroll
    for (int j = 0; j < 8; ++j) o[j] = f2b(p[j]);
    *(ushort8*)(d + (size_t)i * 8) = o;
}

// ---------------------------------------------------------------------------
// Kernel 1: q/k/v projection, bf16 MFMA, bf16 output scattered to [B,H,T,D].
// ---------------------------------------------------------------------------
__global__ __launch_bounds__(256) void proj_qkv_kernel(
    const u16* __restrict__ xb,
    const u16* __restrict__ wq, const u16* __restrict__ wk,
    const u16* __restrict__ wv,
    u16* __restrict__ qo, u16* __restrict__ ko, u16* __restrict__ vo)
{
    const int z = blockIdx.z;
    const u16* Bsel = (z == 0) ? wq : ((z == 1) ? wk : wv);
    u16* Osel       = (z == 0) ? qo : ((z == 1) ? ko : vo);

    const int m0 = blockIdx.x * 128;
    const int n0 = blockIdx.y * 128;
    const int tid = threadIdx.x, lane = tid & 63, wid = tid >> 6;
    const int wm = (wid >> 1) * 64, wn = (wid & 1) * 64;

    __shared__ u16 As[128 * 64];
    __shared__ u16 Bs[128 * 64];

    f32x4 acc[4][4];
#pragma unroll
    for (int a = 0; a < 4; ++a)
#pragma unroll
        for (int b = 0; b < 4; ++b) acc[a][b] = (f32x4){0.f, 0.f, 0.f, 0.f};

    for (int kt = 0; kt < CC; kt += 64) {
#pragma unroll
        for (int i = 0; i < 4; ++i) {
            int slot = i * 256 + tid;
            int row = slot >> 3, c = slot & 7;
            int gc = c ^ (row & 7);
            GLOAD16(xb   + (size_t)(m0 + row) * CC + kt + gc * 8,
                    (char*)As + slot * 16);
            GLOAD16(Bsel + (size_t)(n0 + row) * CC + kt + gc * 8,
                    (char*)Bs + slot * 16);
        }
        asm volatile("s_waitcnt vmcnt(0)" ::: "memory");
        __syncthreads();

#pragma unroll
        for (int kh = 0; kh < 2; ++kh) {
            short8 af[4], bf[4];
            const int lc = kh * 4 + (lane >> 4);
#pragma unroll
            for (int mi = 0; mi < 4; ++mi) {
                int row = wm + mi * 16 + (lane & 15);
                af[mi] = *(const short8*)((const char*)As + row * 128
                                          + ((lc ^ (row & 7)) * 16));
            }
#pragma unroll
            for (int ni = 0; ni < 4; ++ni) {
                int row = wn + ni * 16 + (lane & 15);
                bf[ni] = *(const short8*)((const char*)Bs + row * 128
                                          + ((lc ^ (row & 7)) * 16));
            }
#pragma unroll
            for (int mi = 0; mi < 4; ++mi)
#pragma unroll
                for (int ni = 0; ni < 4; ++ni)
                    acc[mi][ni] = __builtin_amdgcn_mfma_f32_16x16x32_bf16(
                        af[mi], bf[ni], acc[mi][ni], 0, 0, 0);
        }
        __syncthreads();
    }

#pragma unroll
    for (int mi = 0; mi < 4; ++mi) {
#pragma unroll
        for (int ni = 0; ni < 4; ++ni) {
            int n = n0 + wn + ni * 16 + (lane & 15);
            int mbase = m0 + wm + mi * 16 + ((lane >> 4) << 2);
            int h = n >> 6, d = n & 63;
#pragma unroll
            for (int r = 0; r < 4; ++r) {
                int m = mbase + r;
                int b = m >> 11, t = m & 2047;
                Osel[(((size_t)b * HH + h) * TT + t) * DD + d] =
                    f2b(acc[mi][ni][r]);
            }
        }
    }
}

// ---------------------------------------------------------------------------
// Kernel 2 (prep, parallel over 768 chunks). Round-8 rewrite:
//  - MFMA transpose (identity A-operand) builds Kt/Vt: no scalar LDS
//    transpose loop, exact.
//  - Register-resident forward substitution: each lane keeps its column
//    slice T[g+4m][j] in Treg[16]; DPP butterfly broadcasts each new row
//    to all 4 lanes. Critical path has NO LDS round trip (As reads are
//    dependency-free, imm-offset ds_read_b32, wave-broadcast).
//  - LDS pool 49KB with lifetime aliasing -> 3 blocks/CU.
// Outputs: U (bf16 C-frag), P (fp32 C-frag, split A/B), Mtn, Rtn (bf16
// B-frag-major) -- identical layouts/values to round 7.
// ---------------------------------------------------------------------------
__global__ __launch_bounds__(256, 3) void ttt_prep3_kernel(
    const u16* __restrict__ kb, const u16* __restrict__ vb,
    const float* __restrict__ lr_scale,
    u16* __restrict__ ubg, float* __restrict__ pfA, float* __restrict__ pfB,
    u16* __restrict__ mtng, u16* __restrict__ rtng)
{
    const int bx = blockIdx.x;
    const int bh = bx >> 5;
    const int h = bh % HH;
    const float lr = 0.01f * lr_scale[h];
    const u16* kc = kb + (size_t)bx * 4096;
    const u16* vc = vb + (size_t)bx * 4096;
    u16* ubc  = ubg + (size_t)bx * 4096;
    float* pfc = (bx < 384) ? pfA + (size_t)bx * 4096
                            : pfB + (size_t)(bx - 384) * 4096;
    u16* mtnc = mtng + (size_t)bx * 4096;
    u16* rtnc = rtng + (size_t)bx * 4096;

    const int tid = threadIdx.x, lane = tid & 63, wid = tid >> 6;
    const int wm = (wid >> 1) * 32, wn = (wid & 1) * 32;
    const int ar0 = wm + (lane & 15);
    const int br0 = wn + (lane & 15);
    const int lcb = lane >> 4;
    const int or0 = wm + ((lane >> 4) << 2);
    const int oc0 = wn + (lane & 15);

    // LDS pool, 50176 B. Lifetimes:
    //  Kl,Vl: stage -> phase1 frags (dead after b1)   -> reused as Rb,Ub
    //  KtB: phase1 -> end.  VtB: phase1 -> set1       -> reused as TmpB
    //  As(fp32 [64][68]): phase1 -> solve (dead b2)   -> reused as Tb+TmpA
    __shared__ __align__(16) char pool[50176];
    u16* Kl  = (u16*)pool;
    u16* Vl  = (u16*)(pool + 8192);
    u16* KtB = (u16*)(pool + 16384);
    u16* VtB = (u16*)(pool + 24576);
    float (*As)[68] = (float (*)[68])(pool + 32768);
    u16* Rb   = Kl;
    u16* Ub   = Vl;
    u16* TmpB = VtB;
    u16* Tb   = (u16*)(pool + 32768);
    u16* TmpA = (u16*)(pool + 40960);

    // ---- stage K, V (pre-swizzled source, linear LDS dest) ----
#pragma unroll
    for (int i = 0; i < 2; ++i) {
        int slot = i * 256 + tid;
        int row = slot >> 3, cc = slot & 7;
        int gc = cc ^ (row & 7);
        GLOAD16(kc + row * 64 + gc * 8, (char*)Kl + slot * 16);
        GLOAD16(vc + row * 64 + gc * 8, (char*)Vl + slot * 16);
    }
    asm volatile("s_waitcnt vmcnt(0)" ::: "memory");
    __syncthreads();                                            // b0

    // ---- phase 1: aA = K K^T ; aKt = I*K (=K^T); aVt = I*V (=V^T) ----
    {
        // identity A-fragments: I64[m,k], m = ar0+mi*16, k = kh*32+lcb*8+e
        short8 idA[2][2];
#pragma unroll
        for (int mi = 0; mi < 2; ++mi)
#pragma unroll
            for (int kh = 0; kh < 2; ++kh) {
                short8 idf = {0, 0, 0, 0, 0, 0, 0, 0};
#pragma unroll
                for (int e = 0; e < 8; ++e)
                    if (kh * 32 + lcb * 8 + e == ar0 + mi * 16)
                        idf[e] = (short)0x3F80;   // bf16 1.0
                idA[mi][kh] = idf;
            }

        f32x4 aA[2][2], aKt[2][2], aVt[2][2];
#pragma unroll
        for (int a = 0; a < 2; ++a)
#pragma unroll
            for (int b = 0; b < 2; ++b) {
                aA[a][b]  = (f32x4){0.f, 0.f, 0.f, 0.f};
                aKt[a][b] = (f32x4){0.f, 0.f, 0.f, 0.f};
                aVt[a][b] = (f32x4){0.f, 0.f, 0.f, 0.f};
            }
#pragma unroll
        for (int kh = 0; kh < 2; ++kh) {
            short8 ka[2], kbb[2], vbb[2];
#pragma unroll
            for (int i = 0; i < 2; ++i) {
                ka[i]  = ld_frag(Kl, ar0 + i * 16, kh * 4 + lcb);
                kbb[i] = ld_frag(Kl, br0 + i * 16, kh * 4 + lcb);
                vbb[i] = ld_frag(Vl, br0 + i * 16, kh * 4 + lcb);
            }
#pragma unroll
            for (int mi = 0; mi < 2; ++mi)
#pragma unroll
                for (int ni = 0; ni < 2; ++ni) {
                    aA[mi][ni] = __builtin_amdgcn_mfma_f32_16x16x32_bf16(
                        ka[mi], kbb[ni], aA[mi][ni], 0, 0, 0);
                    aKt[mi][ni] = __builtin_amdgcn_mfma_f32_16x16x32_bf16(
                        idA[mi][kh], kbb[ni], aKt[mi][ni], 0, 0, 0);
                    aVt[mi][ni] = __builtin_amdgcn_mfma_f32_16x16x32_bf16(
                        idA[mi][kh], vbb[ni], aVt[mi][ni], 0, 0, 0);
                }
        }
#pragma unroll
        for (int mi = 0; mi < 2; ++mi)
#pragma unroll
            for (int ni = 0; ni < 2; ++ni)
#pragma unroll
                for (int r = 0; r < 4; ++r) {
                    int t = or0 + mi * 16 + r, s = oc0 + ni * 16;
                    As[t][s] = (t > s) ? lr * aA[mi][ni][r] : 0.f;
                    st_sw(KtB, t, s, f2b(aKt[mi][ni][r]));  // Kt[dim][time]
                    st_sw(VtB, t, s, f2b(aVt[mi][ni][r]));  // Vt[dim][time]
                }
    }
    __syncthreads();                                            // b1

    // ---- register-resident forward substitution ----
    // T[t][j] = delta(t,j) - sum_{s<t} A[t][s] T[s][j]; lane (j,g) keeps
    // Treg[m] = T[g+4m][j]. DPP butterfly leaves each row's value in all
    // 4 quad lanes, so no LDS traffic on the serial chain.
    const int j = wid * 16 + (lane >> 2), g = lane & 3;
    float Treg[16];
#pragma unroll
    for (int m = 0; m < 16; ++m) Treg[m] = 0.f;
#pragma unroll
    for (int t = 0; t < 64; ++t) {
        float sum = 0.f;
#pragma unroll
        for (int m = 0; m <= (t >> 2); ++m)
            sum += As[t][g + 4 * m] * Treg[m];   // Treg[m]=0 for rows >= t
        sum = dpp_xadd<0xB1>(sum);
        sum = dpp_xadd<0x4E>(sum);
        float v = ((t == j) ? 1.f : 0.f) - sum;
        if ((t & 3) == g) Treg[t >> 2] = v;      // static index (t unrolled)
    }
    __syncthreads();                                            // b2 (As dead)

    // Tb = bf16(T), row-major [t][s], from registers (Tb aliases As)
#pragma unroll
    for (int m = 0; m < 16; ++m) st_sw(Tb, g + 4 * m, j, f2b(Treg[m]));
    __syncthreads();                                            // b3

    // ---- set1: R = lr*mfma(Kt,T); U = lr*mfma(Vt,T); Rtn = -lr*mfma(T,Kt)
    {
        f32x4 aR[2][2], aU[2][2], aRt[2][2];
#pragma unroll
        for (int a = 0; a < 2; ++a)
#pragma unroll
            for (int b = 0; b < 2; ++b) {
                aR[a][b]  = (f32x4){0.f, 0.f, 0.f, 0.f};
                aU[a][b]  = (f32x4){0.f, 0.f, 0.f, 0.f};
                aRt[a][b] = (f32x4){0.f, 0.f, 0.f, 0.f};
            }
#pragma unroll
        for (int kh = 0; kh < 2; ++kh) {
            short8 kta[2], vta[2], ta[2], tbf[2], ktb[2];
#pragma unroll
            for (int i = 0; i < 2; ++i) {
                kta[i] = ld_frag(KtB, ar0 + i * 16, kh * 4 + lcb);
                vta[i] = ld_frag(VtB, ar0 + i * 16, kh * 4 + lcb);
                ta[i]  = ld_frag(Tb,  ar0 + i * 16, kh * 4 + lcb);
                tbf[i] = ld_frag(Tb,  br0 + i * 16, kh * 4 + lcb);
                ktb[i] = ld_frag(KtB, br0 + i * 16, kh * 4 + lcb);
            }
#pragma unroll
            for (int mi = 0; mi < 2; ++mi)
#pragma unroll
                for (int ni = 0; ni < 2; ++ni) {
                    aR[mi][ni] = __builtin_amdgcn_mfma_f32_16x16x32_bf16(
                        kta[mi], tbf[ni], aR[mi][ni], 0, 0, 0);
                    aU[mi][ni] = __builtin_amdgcn_mfma_f32_16x16x32_bf16(
                        vta[mi], tbf[ni], aU[mi][ni], 0, 0, 0);
                    aRt[mi][ni] = __builtin_amdgcn_mfma_f32_16x16x32_bf16(
                        ta[mi], ktb[ni], aRt[mi][ni], 0, 0, 0);
                }
        }
#pragma unroll
        for (int mi = 0; mi < 2; ++mi)
#pragma unroll
            for (int ni = 0; ni < 2; ++ni) {
                u16 ue[4];
#pragma unroll
                for (int r = 0; r < 4; ++r) {
                    int ro = or0 + mi * 16 + r, co = oc0 + ni * 16;
                    st_sw(Rb, ro, co, f2b(lr * aR[mi][ni][r]));
                    ue[r] = f2b(lr * aU[mi][ni][r]);
                    st_sw(Ub, ro, co, ue[r]);
                    st_sw(TmpA, ro, co, f2b(-lr * aRt[mi][ni][r]));
                }
                uint2 uo;
                uo.x = (unsigned)ue[0] | ((unsigned)ue[1] << 16);
                uo.y = (unsigned)ue[2] | ((unsigned)ue[3] << 16);
                *(uint2*)&ubc[(size_t)((((wid * 2 + mi) * 2 + ni) * 64
                                        + lane) * 4)] = uo;
            }
    }
    __syncthreads();                                            // b4

    // ---- set2: Mtn = -mfma(Kt,R) -> TmpB ; P = mfma(U,Kt) -> global fp32
    {
        f32x4 aM[2][2], aP[2][2];
#pragma unroll
        for (int a = 0; a < 2; ++a)
#pragma unroll
            for (int b = 0; b < 2; ++b) {
                aM[a][b] = (f32x4){0.f, 0.f, 0.f, 0.f};
                aP[a][b] = (f32x4){0.f, 0.f, 0.f, 0.f};
            }
#pragma unroll
        for (int kh = 0; kh < 2; ++kh) {
            short8 kta[2], ua[2], rbb[2], ktb[2];
#pragma unroll
            for (int i = 0; i < 2; ++i) {
                kta[i] = ld_frag(KtB, ar0 + i * 16, kh * 4 + lcb);
                ua[i]  = ld_frag(Ub,  ar0 + i * 16, kh * 4 + lcb);
                rbb[i] = ld_frag(Rb,  br0 + i * 16, kh * 4 + lcb);
                ktb[i] = ld_frag(KtB, br0 + i * 16, kh * 4 + lcb);
            }
#pragma unroll
            for (int mi = 0; mi < 2; ++mi)
#pragma unroll
                for (int ni = 0; ni < 2; ++ni) {
                    aM[mi][ni] = __builtin_amdgcn_mfma_f32_16x16x32_bf16(
                        kta[mi], rbb[ni], aM[mi][ni], 0, 0, 0);
                    aP[mi][ni] = __builtin_amdgcn_mfma_f32_16x16x32_bf16(
                        ua[mi], ktb[ni], aP[mi][ni], 0, 0, 0);
                }
        }
#pragma unroll
        for (int mi = 0; mi < 2; ++mi)
#pragma unroll
            for (int ni = 0; ni < 2; ++ni) {
#pragma unroll
                for (int r = 0; r < 4; ++r)
                    st_sw(TmpB, or0 + mi * 16 + r, oc0 + ni * 16,
                          f2b(-aM[mi][ni][r]));
                *(f32x4*)&pfc[(size_t)((((wid * 2 + mi) * 2 + ni) * 64
                                        + lane) * 4)] = aP[mi][ni];
            }
    }
    // Rtn B-frag-major global store (TmpA written before b4)
    if (wid < 2) {
#pragma unroll
        for (int ni = 0; ni < 2; ++ni)
#pragma unroll
            for (int kh = 0; kh < 2; ++kh) {
                short8 v = ld_frag(TmpA, (wid & 1) * 32 + ni * 16 + (lane & 15),
                                   kh * 4 + lcb);
                *(short8*)&rtnc[(size_t)(((((wid & 1) * 2 + ni) * 2 + kh) * 64
                                          + lane) * 8)] = v;
            }
    }
    __syncthreads();                                            // b5
    // Mtn B-frag-major global store
    if (wid < 2) {
#pragma unroll
        for (int ni = 0; ni < 2; ++ni)
#pragma unroll
            for (int kh = 0; kh < 2; ++kh) {
                short8 v = ld_frag(TmpB, (wid & 1) * 32 + ni * 16 + (lane & 15),
                                   kh * 4 + lcb);
                *(short8*)&mtnc[(size_t)(((((wid & 1) * 2 + ni) * 2 + kh) * 64
                                          + lane) * 8)] = v;
            }
    }
}

// ---------------------------------------------------------------------------
// Kernel 3 (seq): one block per chain; per chunk the ONLY serial work is
//   store W_c (bf16, row-major -> global  [aliased over consumed Mtn])
//   Delta = P_c + W_c * Mtn_c   (acc-init P, 8 MFMA) ;  accW += Delta.
// ---------------------------------------------------------------------------
__global__ __launch_bounds__(256, 1) void ttt_seq_kernel(
    u16* __restrict__ mtnW, const float* __restrict__ pfA,
    const float* __restrict__ pfB)
{
    const int bh = blockIdx.x;
    const int bx0 = bh * NCH;
    const int tid = threadIdx.x, lane = tid & 63, wid = tid >> 6;
    const int wm = (wid >> 1) * 32, wn = (wid & 1) * 32;
    const int ar0 = wm + (lane & 15);
    const int lcb = lane >> 4;
    const int or0 = wm + ((lane >> 4) << 2);
    const int oc0 = wn + (lane & 15);
    const int wn2 = wid & 1;

    __shared__ u16 Wb[4096];

    f32x4 accW[2][2];
#pragma unroll
    for (int a = 0; a < 2; ++a)
#pragma unroll
        for (int b = 0; b < 2; ++b) accW[a][b] = (f32x4){0.f, 0.f, 0.f, 0.f};

    auto ldMtn = [&](int c, short8 (&m)[2][2]) {
        const u16* mb = mtnW + (size_t)(bx0 + c) * 4096;
#pragma unroll
        for (int ni = 0; ni < 2; ++ni)
#pragma unroll
            for (int kh = 0; kh < 2; ++kh)
                m[ni][kh] = *(const short8*)&mb[(size_t)(
                    (((wn2 * 2 + ni) * 2 + kh) * 64 + lane) * 8)];
    };
    auto ldPf = [&](int c, f32x4 (&p)[2][2]) {
        int bx = bx0 + c;
        const float* pb = (bx < 384) ? pfA + (size_t)bx * 4096
                                     : pfB + (size_t)(bx - 384) * 4096;
#pragma unroll
        for (int mi = 0; mi < 2; ++mi)
#pragma unroll
            for (int ni = 0; ni < 2; ++ni)
                p[mi][ni] = *(const f32x4*)&pb[(size_t)(
                    (((wid * 2 + mi) * 2 + ni) * 64 + lane) * 4)];
    };

    auto body = [&](int c, short8 (&cm)[2][2], f32x4 (&cp)[2][2],
                    short8 (&nm)[2][2], f32x4 (&np)[2][2]) {
        asm volatile("s_waitcnt vmcnt(0)" ::: "memory");
        u16* wcp = mtnW + (size_t)(bx0 + c) * 4096;
#pragma unroll
        for (int mi = 0; mi < 2; ++mi)
#pragma unroll
            for (int ni = 0; ni < 2; ++ni)
#pragma unroll
                for (int r = 0; r < 4; ++r) {
                    u16 v = f2b(accW[mi][ni][r]);
                    wcp[(or0 + mi * 16 + r) * 64 + oc0 + ni * 16] = v;
                    st_sw(Wb, or0 + mi * 16 + r, oc0 + ni * 16, v);
                }
        if (c + 1 < NCH) { ldMtn(c + 1, nm); ldPf(c + 1, np); }
        __syncthreads();
        short8 wf[2][2];
#pragma unroll
        for (int mi = 0; mi < 2; ++mi)
#pragma unroll
            for (int kh = 0; kh < 2; ++kh)
                wf[mi][kh] = ld_frag(Wb, ar0 + mi * 16, kh * 4 + lcb);
#pragma unroll
        for (int mi = 0; mi < 2; ++mi)
#pragma unroll
            for (int ni = 0; ni < 2; ++ni) {
                f32x4 d = cp[mi][ni];
#pragma unroll
                for (int kh = 0; kh < 2; ++kh)
                    d = __builtin_amdgcn_mfma_f32_16x16x32_bf16(
                        wf[mi][kh], cm[ni][kh], d, 0, 0, 0);
                accW[mi][ni] = accW[mi][ni] + d;
            }
        __syncthreads();
    };

    short8 mA[2][2], mB[2][2];
    f32x4 pA[2][2], pB[2][2];
    ldMtn(0, mA); ldPf(0, pA);
    for (int c = 0; c < NCH; c += 2) {
        body(c,     mA, pA, mB, pB);
        body(c + 1, mB, pB, mA, pA);
    }
}

// ---------------------------------------------------------------------------
// Kernel 4 (outgen, parallel over 768 chunks):
//   S = stril(Q K^T); Etn = U + W * Rtn; Out = Q W^T + S Etn^T -> hidden.
// ---------------------------------------------------------------------------
__global__ __launch_bounds__(256) void ttt_outgen_kernel(
    const u16* __restrict__ qb, const u16* __restrict__ kb,
    const u16* __restrict__ wcg, const u16* __restrict__ rtng,
    const u16* __restrict__ ubg, u16* __restrict__ hid)
{
    const int bx = blockIdx.x;
    const int bh = bx >> 5, c = bx & 31;
    const int b = bh / HH, h = bh % HH;
    const u16* qc = qb + (size_t)bx * 4096;
    const u16* kc = kb + (size_t)bx * 4096;
    const u16* wcc = wcg + (size_t)bx * 4096;
    const u16* rtnc = rtng + (size_t)bx * 4096;
    const u16* ubc = ubg + (size_t)bx * 4096;
    u16* hch = hid + (size_t)b * TT * CC + h * DD;

    const int tid = threadIdx.x, lane = tid & 63, wid = tid >> 6;
    const int wm = (wid >> 1) * 32, wn = (wid & 1) * 32;
    const int ar0 = wm + (lane & 15);
    const int br0 = wn + (lane & 15);
    const int lcb = lane >> 4;
    const int or0 = wm + ((lane >> 4) << 2);
    const int oc0 = wn + (lane & 15);
    const int wn2 = wid & 1;

    __shared__ u16 Sl[4096], El[4096];

    short8 Qa[2][2], Kb2[2][2];
#pragma unroll
    for (int i = 0; i < 2; ++i)
#pragma unroll
        for (int kh = 0; kh < 2; ++kh) {
            Qa[i][kh]  = gfrag(qc, ar0 + i * 16, kh * 4 + lcb);
            Kb2[i][kh] = gfrag(kc, br0 + i * 16, kh * 4 + lcb);
        }
    f32x4 aS[2][2];
#pragma unroll
    for (int a = 0; a < 2; ++a)
#pragma unroll
        for (int d = 0; d < 2; ++d) aS[a][d] = (f32x4){0.f, 0.f, 0.f, 0.f};
#pragma unroll
    for (int kh = 0; kh < 2; ++kh)
#pragma unroll
        for (int mi = 0; mi < 2; ++mi)
#pragma unroll
            for (int ni = 0; ni < 2; ++ni)
                aS[mi][ni] = __builtin_amdgcn_mfma_f32_16x16x32_bf16(
                    Qa[mi][kh], Kb2[ni][kh], aS[mi][ni], 0, 0, 0);
#pragma unroll
    for (int mi = 0; mi < 2; ++mi)
#pragma unroll
        for (int ni = 0; ni < 2; ++ni)
#pragma unroll
            for (int r = 0; r < 4; ++r) {
                int t = or0 + mi * 16 + r, s = oc0 + ni * 16;
                st_sw(Sl, t, s, f2b((t > s) ? aS[mi][ni][r] : 0.f));
            }

    f32x4 aE[2][2];
#pragma unroll
    for (int mi = 0; mi < 2; ++mi)
#pragma unroll
        for (int ni = 0; ni < 2; ++ni) {
            uint2 uu = *(const uint2*)&ubc[(size_t)(
                (((wid * 2 + mi) * 2 + ni) * 64 + lane) * 4)];
            f32x4 e;
            e[0] = b2f((u16)(uu.x & 0xFFFF)); e[1] = b2f((u16)(uu.x >> 16));
            e[2] = b2f((u16)(uu.y & 0xFFFF)); e[3] = b2f((u16)(uu.y >> 16));
            aE[mi][ni] = e;
        }
    short8 Wa[2][2], Rtb[2][2];
#pragma unroll
    for (int i = 0; i < 2; ++i)
#pragma unroll
        for (int kh = 0; kh < 2; ++kh) {
            Wa[i][kh] = gfrag(wcc, ar0 + i * 16, kh * 4 + lcb);
            Rtb[i][kh] = *(const short8*)&rtnc[(size_t)(
                (((wn2 * 2 + i) * 2 + kh) * 64 + lane) * 8)];
        }
#pragma unroll
    for (int kh = 0; kh < 2; ++kh)
#pragma unroll
        for (int mi = 0; mi < 2; ++mi)
#pragma unroll
            for (int ni = 0; ni < 2; ++ni)
                aE[mi][ni] = __builtin_amdgcn_mfma_f32_16x16x32_bf16(
                    Wa[mi][kh], Rtb[ni][kh], aE[mi][ni], 0, 0, 0);
#pragma unroll
    for (int mi = 0; mi < 2; ++mi)
#pragma unroll
        for (int ni = 0; ni < 2; ++ni)
#pragma unroll
            for (int r = 0; r < 4; ++r)
                st_sw(El, or0 + mi * 16 + r, oc0 + ni * 16,
                      f2b(aE[mi][ni][r]));
    __syncthreads();

    f32x4 aO[2][2];
#pragma unroll
    for (int a = 0; a < 2; ++a)
#pragma unroll
        for (int d = 0; d < 2; ++d) aO[a][d] = (f32x4){0.f, 0.f, 0.f, 0.f};
#pragma unroll
    for (int kh = 0; kh < 2; ++kh) {
        short8 Wb2[2], Sa[2], Eb[2];
#pragma unroll
        for (int i = 0; i < 2; ++i) {
            Wb2[i] = gfrag(wcc, br0 + i * 16, kh * 4 + lcb);
            Sa[i]  = ld_frag(Sl, ar0 + i * 16, kh * 4 + lcb);
            Eb[i]  = ld_frag(El, br0 + i * 16, kh * 4 + lcb);
        }
#pragma unroll
        for (int mi = 0; mi < 2; ++mi)
#pragma unroll
            for (int ni = 0; ni < 2; ++ni) {
                aO[mi][ni] = __builtin_amdgcn_mfma_f32_16x16x32_bf16(
                    Qa[mi][kh], Wb2[ni], aO[mi][ni], 0, 0, 0);
                aO[mi][ni] = __builtin_amdgcn_mfma_f32_16x16x32_bf16(
                    Sa[mi], Eb[ni], aO[mi][ni], 0, 0, 0);
            }
    }
#pragma unroll
    for (int mi = 0; mi < 2; ++mi)
#pragma unroll
        for (int ni = 0; ni < 2; ++ni)
#pragma unroll
            for (int r = 0; r < 4; ++r)
                hch[(size_t)(c * CL + or0 + mi * 16 + r) * CC
                    + oc0 + ni * 16] = f2b(aO[mi][ni][r]);
}

// ---------------------------------------------------------------------------
// Kernel 5: output projection (bf16 MFMA, fp32 row-major out).
// ---------------------------------------------------------------------------
__global__ __launch_bounds__(256) void out_proj_kernel(
    const u16* __restrict__ hid, const u16* __restrict__ wo,
    float* __restrict__ out)
{
    const int m0 = blockIdx.x * 128;
    const int n0 = blockIdx.y * 128;
    const int tid = threadIdx.x, lane = tid & 63, wid = tid >> 6;
    const int wm = (wid >> 1) * 64, wn = (wid & 1) * 64;

    __shared__ u16 As[128 * 64];
    __shared__ u16 Bs[128 * 64];

    f32x4 acc[4][4];
#pragma unroll
    for (int a = 0; a < 4; ++a)
#pragma unroll
        for (int b = 0; b < 4; ++b) acc[a][b] = (f32x4){0.f, 0.f, 0.f, 0.f};

    for (int kt = 0; kt < CC; kt += 64) {
#pragma unroll
        for (int i = 0; i < 4; ++i) {
            int slot = i * 256 + tid;
            int row = slot >> 3, c = slot & 7;
            int gc = c ^ (row & 7);
            GLOAD16(hid + (size_t)(m0 + row) * CC + kt + gc * 8,
                    (char*)As + slot * 16);
            GLOAD16(wo  + (size_t)(n0 + row) * CC + kt + gc * 8,
                    (char*)Bs + slot * 16);
        }
        asm volatile("s_waitcnt vmcnt(0)" ::: "memory");
        __syncthreads();

#pragma unroll
        for (int kh = 0; kh < 2; ++kh) {
            short8 af[4], bf[4];
            const int lc = kh * 4 + (lane >> 4);
#pragma unroll
            for (int mi = 0; mi < 4; ++mi) {
                int row = wm + mi * 16 + (lane & 15);
                af[mi] = *(const short8*)((const char*)As + row * 128
                                          + ((lc ^ (row & 7)) * 16));
            }
#pragma unroll
            for (int ni = 0; ni < 4; ++ni) {
                int row = wn + ni * 16 + (lane & 15);
                bf[ni] = *(const short8*)((const char*)Bs + row * 128
                                          + ((lc ^ (row & 7)) * 16));
            }
#pragma unroll
            for (int mi = 0; mi < 4; ++mi)
#pragma unroll
                for (int ni = 0; ni < 4; ++ni)
                    acc[mi][ni] = __builtin_amdgcn_mfma_f32_16x16x32_bf16(
                        af[mi], bf[ni], acc[mi][ni], 0, 0, 0);
        }
        __syncthreads();
    }

#pragma unroll
    for (int mi = 0; mi < 4; ++mi) {
#pragma unroll
        for (int ni = 0; ni < 4; ++ni) {
            int n = n0 + wn + ni * 16 + (lane & 15);
            int mbase = m0 + wm + mi * 16 + ((lane >> 4) << 2);
#pragma unroll
            for (int r = 0; r < 4; ++r)
                out[(size_t)(mbase + r) * CC + n] = acc[mi][ni][r];
        }
    }
}

// ---------------------------------------------------------------------------
extern "C" void kernel_launch(void* const* d_in, const int* in_sizes, int n_in,
                              void* d_out, int out_size, void* d_ws, size_t ws_size,
                              hipStream_t stream) {
    const float* x  = (const float*)d_in[0];
    const float* Wq = (const float*)d_in[1];
    const float* Wk = (const float*)d_in[2];
    const float* Wv = (const float*)d_in[3];
    const float* Wo = (const float*)d_in[4];
    const float* lr = (const float*)d_in[5];

    // workspace: 7*NQ + 4*WSZ u16 (same proven size). Aliases:
    //  slot2: vb -> Ub ; slot3: xb -> pfA(fp32) -> hid
    //  slot4: Mtn -> Wc ; slot6: pfB (fp32 half of P)
    u16* us   = (u16*)d_ws;
    u16* qb   = us;
    u16* kbw  = us + (size_t)NQ;
    u16* vbw  = us + (size_t)2 * NQ;    // -> Ub
    u16* xb   = us + (size_t)3 * NQ;    // -> pfA -> hid
    u16* mtnW = us + (size_t)4 * NQ;    // -> Wc
    u16* rtn  = us + (size_t)5 * NQ;
    float* pfB = (float*)(us + (size_t)6 * NQ);
    u16* wqb = us + (size_t)7 * NQ;
    u16* wkb = wqb + WSZ;
    u16* wvb = wkb + WSZ;
    u16* wob = wvb + WSZ;
    u16* ub  = vbw;
    float* pfA = (float*)xb;
    u16* hid = xb;

    // 0) fp32 -> bf16
    cvt5_kernel<<<dim3((NQ / 8 + 255) / 256, 5), 256, 0, stream>>>(
        x, Wq, Wk, Wv, Wo, xb, wqb, wkb, wvb, wob);

    // 1) q/k/v projections (bf16 out, [B,H,T,D])
    proj_qkv_kernel<<<dim3(NN / 128, CC / 128, 3), 256, 0, stream>>>(
        xb, wqb, wkb, wvb, qb, kbw, vbw);

    // 2) prep: per-chunk U, P, Mtn, Rtn (768 parallel blocks, 3 blk/CU)
    ttt_prep3_kernel<<<dim3(NCHUNKS), 256, 0, stream>>>(
        kbw, vbw, lr, ub, pfA, pfB, mtnW, rtn);

    // 3) seq: W-chain only, 24 blocks, 1 gemm per chunk
    ttt_seq_kernel<<<dim3(BB * HH), 256, 0, stream>>>(mtnW, pfA, pfB);

    // 4) outgen: per-chunk hidden output (768 parallel blocks)
    ttt_outgen_kernel<<<dim3(NCHUNKS), 256, 0, stream>>>(
        qb, kbw, mtnW, rtn, ub, hid);

    // 5) output projection
    out_proj_kernel<<<dim3(NN / 128, CC / 128), 256, 0, stream>>>(
        hid, wob, (float*)d_out);
}